// Round 6
// baseline (503.531 us; speedup 1.0000x reference)
//
#include <hip/hip_runtime.h>

#define CH 128
#define CHUNK 4096

typedef float v2f __attribute__((ext_vector_type(2)));

// ---------------------------------------------------------------- fp8 helpers (OCP e4m3)

__device__ __forceinline__ void fp8acc4(unsigned w, float* a) {
  v2f p0 = __builtin_amdgcn_cvt_pk_f32_fp8(w, false);
  v2f p1 = __builtin_amdgcn_cvt_pk_f32_fp8(w, true);
  a[0] += p0.x; a[1] += p0.y; a[2] += p1.x; a[3] += p1.y;
}
__device__ __forceinline__ void fp8acc16(uint4 v, float* a) {
  fp8acc4(v.x, a); fp8acc4(v.y, a + 4); fp8acc4(v.z, a + 8); fp8acc4(v.w, a + 12);
}
__device__ __forceinline__ void fp8wacc4(unsigned w, float wt, float* a) {
  v2f p0 = __builtin_amdgcn_cvt_pk_f32_fp8(w, false);
  v2f p1 = __builtin_amdgcn_cvt_pk_f32_fp8(w, true);
  a[0] += wt * p0.x; a[1] += wt * p0.y; a[2] += wt * p1.x; a[3] += wt * p1.y;
}
__device__ __forceinline__ void fp8st4(unsigned w, float* d) {
  v2f p0 = __builtin_amdgcn_cvt_pk_f32_fp8(w, false);
  v2f p1 = __builtin_amdgcn_cvt_pk_f32_fp8(w, true);
  d[0] = p0.x; d[1] = p0.y; d[2] = p1.x; d[3] = p1.y;
}
__device__ __forceinline__ unsigned fp8pk4(float a, float b, float c, float d) {
  int w = 0;
  w = __builtin_amdgcn_cvt_pk_fp8_f32(a, b, w, false);
  w = __builtin_amdgcn_cvt_pk_fp8_f32(c, d, w, true);
  return (unsigned)w;
}

// ---------------------------------------------------------------- utilities

__device__ __forceinline__ int edge_at(const void* ei, long long i, int is64) {
  if (is64) return (int)((const long long*)ei)[i];
  return ((const int*)ei)[i];
}

__global__ void k_detect(const int* ei, int* flag) {
  if (blockIdx.x == 0 && threadIdx.x == 0) {
    int is64 = 1;
    for (int k = 1; k < 128; k += 2)
      if (ei[k] != 0) { is64 = 0; break; }
    *flag = is64;
  }
}

// zero wp[N], S[CH], bcnt[256]
__global__ void k_init(float* wp, float* S, int* bcnt, int N) {
  int i = blockIdx.x * 256 + threadIdx.x;
  if (i < N) wp[i] = 0.f;
  if (blockIdx.x == 0) {
    int t = threadIdx.x;
    bcnt[t] = 0;
    if (t < CH) S[t] = 0.f;
  }
}

// P1: per-bucket edge counts (bucket = c >> 8)
__global__ __launch_bounds__(256) void kb_count(const void* ei, const int* flag,
                                                int* bcnt, int E, int N) {
  __shared__ int hist[256];
  int t = threadIdx.x;
  hist[t] = 0;
  __syncthreads();
  int f = *flag;
  for (int e = blockIdx.x * 256 + t; e < E; e += gridDim.x * 256) {
    int r = edge_at(ei, e, f);
    int c = edge_at(ei, (long long)E + e, f);
    if ((unsigned)r < (unsigned)N && (unsigned)c < (unsigned)N)
      atomicAdd(&hist[c >> 8], 1);
  }
  __syncthreads();
  if (hist[t] > 0) atomicAdd(&bcnt[t], hist[t]);
}

// P2: scan bucket counts -> bases + cursors; rowptr[N]=total
__global__ void kb_scan(const int* bcnt, int* bbase, int* gcursor, int* rowptr,
                        int NB, int N) {
  __shared__ int tmp[256];
  int t = threadIdx.x;
  int v = (t < NB) ? bcnt[t] : 0;
  tmp[t] = v;
  __syncthreads();
  for (int off = 1; off < 256; off <<= 1) {
    int u = (t >= off) ? tmp[t - off] : 0;
    __syncthreads();
    tmp[t] += u;
    __syncthreads();
  }
  int excl = tmp[t] - v;
  bbase[t] = excl;
  gcursor[t] = excl;
  if (t == 255) rowptr[N] = tmp[255];
}

// P3: bucket-sort edges into pairs[] via LDS staging
__global__ __launch_bounds__(256) void kb_scatter(const void* ei, const int* flag,
                                                  int* gcursor, int2* pairs,
                                                  int E, int N) {
  __shared__ int hist[256], lbase[256], lcur[256], gbl[256], tmp[256];
  __shared__ int2 stage[CHUNK];
  int t = threadIdx.x;
  int e0 = blockIdx.x * CHUNK;
  int f = *flag;
  hist[t] = 0;
  __syncthreads();
  int rr[16], cc[16];
#pragma unroll
  for (int k = 0; k < 16; ++k) {
    int e = e0 + k * 256 + t;
    rr[k] = 0; cc[k] = -1;
    if (e < E) {
      int r = edge_at(ei, e, f);
      int c = edge_at(ei, (long long)E + e, f);
      if ((unsigned)r < (unsigned)N && (unsigned)c < (unsigned)N) {
        rr[k] = r; cc[k] = c;
        atomicAdd(&hist[c >> 8], 1);
      }
    }
  }
  __syncthreads();
  int v = hist[t];
  tmp[t] = v;
  __syncthreads();
  for (int off = 1; off < 256; off <<= 1) {
    int u = (t >= off) ? tmp[t - off] : 0;
    __syncthreads();
    tmp[t] += u;
    __syncthreads();
  }
  lbase[t] = tmp[t] - v;
  lcur[t] = tmp[t] - v;
  if (v > 0) gbl[t] = atomicAdd(&gcursor[t], v);
  __syncthreads();
#pragma unroll
  for (int k = 0; k < 16; ++k) {
    if (cc[k] >= 0) {
      int b = cc[k] >> 8;
      int pos = atomicAdd(&lcur[b], 1);
      stage[pos] = make_int2(rr[k], cc[k]);
    }
  }
  __syncthreads();
  int n = tmp[255];
  for (int i = t; i < n; i += 256) {
    int2 p = stage[i];
    int b = p.y >> 8;
    pairs[gbl[b] + (i - lbase[b])] = p;
  }
}

// P4: per-bucket CSR build + dinv. 1024 threads/block for latency hiding.
__global__ __launch_bounds__(1024) void kb_csr(const int2* __restrict__ pairs,
                                               const int* __restrict__ bcnt,
                                               const int* __restrict__ bbase,
                                               int* rowptr, int* src,
                                               float* dinv, int N) {
  __shared__ int hist[256], lcur[256], tmp[256];
  int t = threadIdx.x;
  int b = blockIdx.x;
  int node0 = b << 8;
  int nn = min(256, N - node0);
  int base = bbase[b];
  int cnt = bcnt[b];
  if (t < 256) hist[t] = 0;
  __syncthreads();
  for (int j = t; j < cnt; j += 1024)
    atomicAdd(&hist[pairs[base + j].y - node0], 1);
  __syncthreads();
  if (t < 256) tmp[t] = hist[t];
  __syncthreads();
  for (int off = 1; off < 256; off <<= 1) {
    int u = (t < 256 && t >= off) ? tmp[t - off] : 0;
    __syncthreads();
    if (t < 256) tmp[t] += u;
    __syncthreads();
  }
  if (t < 256) {
    int v = hist[t];
    lcur[t] = tmp[t] - v;
    if (t < nn) {
      rowptr[node0 + t] = base + tmp[t] - v;
      dinv[node0 + t] = rsqrtf((float)(v + 1));  // +1 self-loop
    }
  }
  __syncthreads();
  for (int j = t; j < cnt; j += 1024) {
    int2 p = pairs[base + j];
    int pos = atomicAdd(&lcur[p.y - node0], 1);
    src[base + pos] = p.x;
  }
}

// P5: wp[r] += dinv[c] over all edges — full-device grid-stride over pairs
__global__ __launch_bounds__(256) void k_wp(const int2* __restrict__ pairs,
                                            const float* __restrict__ dinv,
                                            float* wp, const int* __restrict__ rowptr,
                                            int N) {
  int T = rowptr[N];
  for (int i = blockIdx.x * 256 + threadIdx.x; i < T; i += gridDim.x * 256) {
    int2 p = pairs[i];
    atomicAdd(&wp[p.x], dinv[p.y]);
  }
}

// ---------------------------------------------------------------- GEMMs
// Cb[r,:] = fp8( dinv[r] * (A[r,:] @ W) ), W fp32 128x128

__global__ __launch_bounds__(256) void k_gemm_f32(const float* __restrict__ A,
                                                  const float* __restrict__ W,
                                                  const float* __restrict__ dinv,
                                                  unsigned* __restrict__ Cb, int N) {
  __shared__ float As[64][128];
  __shared__ float Bs[128][64];
  int tid = threadIdx.x;
  int row0 = blockIdx.x * 64;
  int col0 = blockIdx.y * 64;
  {
    int k4 = tid & 31, m = tid >> 5;
    for (int mm = m; mm < 64; mm += 8) {
      int gr = row0 + mm;
      float4 v = make_float4(0.f, 0.f, 0.f, 0.f);
      if (gr < N) v = ((const float4*)A)[(size_t)gr * 32 + k4];
      *(float4*)&As[mm][k4 * 4] = v;
    }
    int n4 = tid & 15, kr = tid >> 4;
    for (int kk = kr; kk < 128; kk += 16) {
      float4 v = ((const float4*)W)[(size_t)kk * 32 + (col0 >> 2) + n4];
      *(float4*)&Bs[kk][n4 * 4] = v;
    }
  }
  __syncthreads();
  int tx = tid & 15, ty = tid >> 4;
  int m0 = ty * 4, n0 = tx * 4;
  float acc[4][4] = {};
#pragma unroll 8
  for (int k = 0; k < 128; ++k) {
    int kk = (k + ty * 33) & 127;
    float a0 = As[m0 + 0][kk], a1 = As[m0 + 1][kk];
    float a2 = As[m0 + 2][kk], a3 = As[m0 + 3][kk];
    float4 b = *(const float4*)&Bs[kk][n0];
    acc[0][0] += a0 * b.x; acc[0][1] += a0 * b.y; acc[0][2] += a0 * b.z; acc[0][3] += a0 * b.w;
    acc[1][0] += a1 * b.x; acc[1][1] += a1 * b.y; acc[1][2] += a1 * b.z; acc[1][3] += a1 * b.w;
    acc[2][0] += a2 * b.x; acc[2][1] += a2 * b.y; acc[2][2] += a2 * b.z; acc[2][3] += a2 * b.w;
    acc[3][0] += a3 * b.x; acc[3][1] += a3 * b.y; acc[3][2] += a3 * b.z; acc[3][3] += a3 * b.w;
  }
#pragma unroll
  for (int i = 0; i < 4; ++i) {
    int gr = row0 + m0 + i;
    if (gr < N) {
      float s = dinv[gr];
      Cb[(size_t)gr * 32 + ((col0 + n0) >> 2)] =
          fp8pk4(acc[i][0] * s, acc[i][1] * s, acc[i][2] * s, acc[i][3] * s);
    }
  }
}

__global__ __launch_bounds__(256) void k_gemm_fp8(const uint4* __restrict__ Ab,
                                                  const float* __restrict__ W,
                                                  const float* __restrict__ dinv,
                                                  unsigned* __restrict__ Cb, int N) {
  __shared__ float As[64][128];
  __shared__ float Bs[128][64];
  int tid = threadIdx.x;
  int row0 = blockIdx.x * 64;
  int col0 = blockIdx.y * 64;
  {
    int k4 = tid & 7, m = tid >> 3;  // 8 uint4 per 128-ch fp8 row
    for (int mm = m; mm < 64; mm += 32) {
      int gr = row0 + mm;
      uint4 v = make_uint4(0, 0, 0, 0);
      if (gr < N) v = Ab[(size_t)gr * 8 + k4];
      float* d = &As[mm][k4 * 16];
      fp8st4(v.x, d); fp8st4(v.y, d + 4); fp8st4(v.z, d + 8); fp8st4(v.w, d + 12);
    }
    int n4 = tid & 15, kr = tid >> 4;
    for (int kk = kr; kk < 128; kk += 16) {
      float4 v = ((const float4*)W)[(size_t)kk * 32 + (col0 >> 2) + n4];
      *(float4*)&Bs[kk][n4 * 4] = v;
    }
  }
  __syncthreads();
  int tx = tid & 15, ty = tid >> 4;
  int m0 = ty * 4, n0 = tx * 4;
  float acc[4][4] = {};
#pragma unroll 8
  for (int k = 0; k < 128; ++k) {
    int kk = (k + ty * 33) & 127;
    float a0 = As[m0 + 0][kk], a1 = As[m0 + 1][kk];
    float a2 = As[m0 + 2][kk], a3 = As[m0 + 3][kk];
    float4 b = *(const float4*)&Bs[kk][n0];
    acc[0][0] += a0 * b.x; acc[0][1] += a0 * b.y; acc[0][2] += a0 * b.z; acc[0][3] += a0 * b.w;
    acc[1][0] += a1 * b.x; acc[1][1] += a1 * b.y; acc[1][2] += a1 * b.z; acc[1][3] += a1 * b.w;
    acc[2][0] += a2 * b.x; acc[2][1] += a2 * b.y; acc[2][2] += a2 * b.z; acc[2][3] += a2 * b.w;
    acc[3][0] += a3 * b.x; acc[3][1] += a3 * b.y; acc[3][2] += a3 * b.z; acc[3][3] += a3 * b.w;
  }
#pragma unroll
  for (int i = 0; i < 4; ++i) {
    int gr = row0 + m0 + i;
    if (gr < N) {
      float s = dinv[gr];
      Cb[(size_t)gr * 32 + ((col0 + n0) >> 2)] =
          fp8pk4(acc[i][0] * s, acc[i][1] * s, acc[i][2] * s, acc[i][3] * s);
    }
  }
}

// ---------------------------------------------------------------- aggregate (fp8)
// out[c,:] = fp8(relu(dinv[c]*(hh[c,:] + sum_{r} hh[r,:]) + bias))
// Row = 128 B fp8: 8 lanes x uint4; 32 node slots per 256-thread block.
__global__ __launch_bounds__(256) void k_aggf(const uint4* __restrict__ hh,
                                              const float* __restrict__ dinv,
                                              const int* __restrict__ rowptr,
                                              const int* __restrict__ src,
                                              const float* __restrict__ bias,
                                              uint4* __restrict__ outb, int N) {
  int tx = threadIdx.x;  // 0..7 : 16-channel chunk
  int ty = threadIdx.y;  // 0..31: node slot
  float bv[16];
#pragma unroll
  for (int i = 0; i < 16; ++i) bv[i] = bias[tx * 16 + i];

  for (int c = blockIdx.x * 32 + ty; c < N; c += gridDim.x * 32) {
    float acc[16] = {};
    fp8acc16(hh[(size_t)c * 8 + tx], acc);  // self-loop
    int j = rowptr[c], je = rowptr[c + 1];
    for (; j + 8 <= je; j += 8) {
      int r0 = src[j + 0], r1 = src[j + 1], r2 = src[j + 2], r3 = src[j + 3];
      int r4 = src[j + 4], r5 = src[j + 5], r6 = src[j + 6], r7 = src[j + 7];
      uint4 v0 = hh[(size_t)r0 * 8 + tx];
      uint4 v1 = hh[(size_t)r1 * 8 + tx];
      uint4 v2 = hh[(size_t)r2 * 8 + tx];
      uint4 v3 = hh[(size_t)r3 * 8 + tx];
      uint4 v4 = hh[(size_t)r4 * 8 + tx];
      uint4 v5 = hh[(size_t)r5 * 8 + tx];
      uint4 v6 = hh[(size_t)r6 * 8 + tx];
      uint4 v7 = hh[(size_t)r7 * 8 + tx];
      fp8acc16(v0, acc); fp8acc16(v1, acc); fp8acc16(v2, acc); fp8acc16(v3, acc);
      fp8acc16(v4, acc); fp8acc16(v5, acc); fp8acc16(v6, acc); fp8acc16(v7, acc);
    }
    for (; j < je; ++j) fp8acc16(hh[(size_t)src[j] * 8 + tx], acc);
    float s = dinv[c];
    float o[16];
#pragma unroll
    for (int i = 0; i < 16; ++i) o[i] = fmaxf(acc[i] * s + bv[i], 0.f);
    uint4 ov;
    ov.x = fp8pk4(o[0], o[1], o[2], o[3]);
    ov.y = fp8pk4(o[4], o[5], o[6], o[7]);
    ov.z = fp8pk4(o[8], o[9], o[10], o[11]);
    ov.w = fp8pk4(o[12], o[13], o[14], o[15]);
    outb[(size_t)c * 8 + tx] = ov;
  }
}

// ---------------------------------------------------------------- layer-3 collapse
// u[ch] = sum_c (dinv[c]+wp[c])*dinv[c] * xb[c,ch]
__global__ __launch_bounds__(256) void k_usumf(const uint4* __restrict__ xb,
                                               const float* __restrict__ wp,
                                               const float* __restrict__ dinv,
                                               float* __restrict__ u, int N) {
  __shared__ float red[32][CH];
  int tx = threadIdx.x;  // 0..7
  int ty = threadIdx.y;  // 0..31
  float acc[16] = {};
  for (int c = blockIdx.x * 32 + ty; c < N; c += gridDim.x * 32) {
    float d = dinv[c];
    float wt = (d + wp[c]) * d;
    uint4 v = xb[(size_t)c * 8 + tx];
    fp8wacc4(v.x, wt, acc); fp8wacc4(v.y, wt, acc + 4);
    fp8wacc4(v.z, wt, acc + 8); fp8wacc4(v.w, wt, acc + 12);
  }
#pragma unroll
  for (int i = 0; i < 16; ++i) red[ty][tx * 16 + i] = acc[i];
  __syncthreads();
  for (int s = 16; s > 0; s >>= 1) {
    if (ty < s) {
#pragma unroll
      for (int i = 0; i < 16; ++i) red[ty][tx * 16 + i] += red[ty + s][tx * 16 + i];
    }
    __syncthreads();
  }
  if (ty == 0) {
#pragma unroll
    for (int i = 0; i < 16; ++i) atomicAdd(&u[tx * 16 + i], red[0][tx * 16 + i]);
  }
}

// ---------------------------------------------------------------- epilogue
__global__ void k_final(const float* __restrict__ u, const float* __restrict__ W3,
                        const float* __restrict__ b3, const float* __restrict__ Wl,
                        const float* __restrict__ bl, float* __restrict__ out,
                        float invN) {
  __shared__ float us[CH];
  __shared__ float red[CH];
  int t = threadIdx.x;
  us[t] = u[t] * invN;
  __syncthreads();
  float s = 0.f;
  for (int k = 0; k < CH; ++k) s += us[k] * W3[(size_t)k * CH + t];
  float g = s + b3[t];
  red[t] = g * Wl[t];
  __syncthreads();
  for (int off = 64; off > 0; off >>= 1) {
    if (t < off) red[t] += red[t + off];
    __syncthreads();
  }
  if (t == 0) out[0] = 1.f / (1.f + expf(-(red[0] + bl[0])));
}

// ---------------------------------------------------------------- launch

extern "C" void kernel_launch(void* const* d_in, const int* in_sizes, int n_in,
                              void* d_out, int out_size, void* d_ws, size_t ws_size,
                              hipStream_t stream) {
  const float* x  = (const float*)d_in[0];
  const void*  ei = d_in[1];
  const float* W1 = (const float*)d_in[3];
  const float* b1 = (const float*)d_in[4];
  const float* W2 = (const float*)d_in[5];
  const float* b2 = (const float*)d_in[6];
  const float* W3 = (const float*)d_in[7];
  const float* b3 = (const float*)d_in[8];
  const float* Wl = (const float*)d_in[9];
  const float* bl = (const float*)d_in[10];
  float* out = (float*)d_out;

  const int N = in_sizes[0] / CH;
  const int E = in_sizes[1] / 2;
  const int NB = (N + 255) >> 8;

  char* ws = (char*)d_ws;
  size_t off = 0;
  auto alloc = [&](size_t bytes) -> void* {
    void* p = ws + off;
    off += (bytes + 511) & ~(size_t)511;
    return p;
  };
  int*   flag   = (int*)alloc(4);
  float* dinv   = (float*)alloc((size_t)N * 4);
  float* wp     = (float*)alloc((size_t)N * 4);
  int*   rowptr = (int*)alloc((size_t)(N + 1) * 4);
  int*   bcnt   = (int*)alloc(256 * 4);
  int*   bbase  = (int*)alloc(256 * 4);
  int*   gcur   = (int*)alloc(256 * 4);
  float* S      = (float*)alloc(CH * 4);
  int*   src    = (int*)alloc((size_t)E * 4);
  int2*  pairs  = (int2*)alloc((size_t)E * 8);
  uint4* hbuf   = (uint4*)alloc((size_t)N * CH);  // fp8 rows (128 B)
  uint4* xbuf   = (uint4*)alloc((size_t)N * CH);  // fp8 rows

  const int nbN = (N + 255) / 256;
  const int nbE = (E + 255) / 256;
  const int nCk = (E + CHUNK - 1) / CHUNK;

  // ---- preprocessing: bucket CSR + dinv + wp
  k_detect<<<1, 64, 0, stream>>>((const int*)ei, flag);
  k_init<<<nbN, 256, 0, stream>>>(wp, S, bcnt, N);
  kb_count<<<nCk, 256, 0, stream>>>(ei, flag, bcnt, E, N);
  kb_scan<<<1, 256, 0, stream>>>(bcnt, bbase, gcur, rowptr, NB, N);
  kb_scatter<<<nCk, 256, 0, stream>>>(ei, flag, gcur, pairs, E, N);
  kb_csr<<<NB, 1024, 0, stream>>>(pairs, bcnt, bbase, rowptr, src, dinv, N);
  k_wp<<<nbE, 256, 0, stream>>>(pairs, dinv, wp, rowptr, N);

  // ---- layers 1 & 2
  dim3 ggrid((N + 63) / 64, 2);
  dim3 ablk(8, 32);
  dim3 agrid((N + 31) / 32);

  k_gemm_f32<<<ggrid, 256, 0, stream>>>(x, W1, dinv, (unsigned*)hbuf, N);
  k_aggf<<<agrid, ablk, 0, stream>>>(hbuf, dinv, rowptr, src, b1, xbuf, N);
  k_gemm_fp8<<<ggrid, 256, 0, stream>>>(xbuf, W2, dinv, (unsigned*)hbuf, N);
  k_aggf<<<agrid, ablk, 0, stream>>>(hbuf, dinv, rowptr, src, b2, xbuf, N);

  // ---- layer 3 collapsed
  k_usumf<<<256, ablk, 0, stream>>>(xbuf, wp, dinv, S, N);
  k_final<<<1, CH, 0, stream>>>(S, W3, b3, Wl, bl, out, 1.0f / (float)N);
}

// Round 7
// 465.558 us; speedup vs baseline: 1.0816x; 1.0816x over previous
//
#include <hip/hip_runtime.h>

#define CH 128
#define CHUNK 4096
#define NBU 256  // k_usumf grid

typedef float v2f __attribute__((ext_vector_type(2)));

// ---------------------------------------------------------------- fp8 helpers (OCP e4m3)

__device__ __forceinline__ void fp8acc4(unsigned w, float* a) {
  v2f p0 = __builtin_amdgcn_cvt_pk_f32_fp8(w, false);
  v2f p1 = __builtin_amdgcn_cvt_pk_f32_fp8(w, true);
  a[0] += p0.x; a[1] += p0.y; a[2] += p1.x; a[3] += p1.y;
}
__device__ __forceinline__ void fp8acc16(uint4 v, float* a) {
  fp8acc4(v.x, a); fp8acc4(v.y, a + 4); fp8acc4(v.z, a + 8); fp8acc4(v.w, a + 12);
}
__device__ __forceinline__ void fp8wacc4(unsigned w, float wt, float* a) {
  v2f p0 = __builtin_amdgcn_cvt_pk_f32_fp8(w, false);
  v2f p1 = __builtin_amdgcn_cvt_pk_f32_fp8(w, true);
  a[0] += wt * p0.x; a[1] += wt * p0.y; a[2] += wt * p1.x; a[3] += wt * p1.y;
}
__device__ __forceinline__ void fp8st4(unsigned w, float* d) {
  v2f p0 = __builtin_amdgcn_cvt_pk_f32_fp8(w, false);
  v2f p1 = __builtin_amdgcn_cvt_pk_f32_fp8(w, true);
  d[0] = p0.x; d[1] = p0.y; d[2] = p1.x; d[3] = p1.y;
}
__device__ __forceinline__ unsigned fp8pk4(float a, float b, float c, float d) {
  int w = 0;
  w = __builtin_amdgcn_cvt_pk_fp8_f32(a, b, w, false);
  w = __builtin_amdgcn_cvt_pk_fp8_f32(c, d, w, true);
  return (unsigned)w;
}

// ---------------------------------------------------------------- utilities

__device__ __forceinline__ int edge_at(const void* ei, long long i, int is64) {
  if (is64) return (int)((const long long*)ei)[i];
  return ((const int*)ei)[i];
}

__global__ void k_detect(const int* ei, int* flag) {
  if (blockIdx.x == 0 && threadIdx.x == 0) {
    int is64 = 1;
    for (int k = 1; k < 128; k += 2)
      if (ei[k] != 0) { is64 = 0; break; }
    *flag = is64;
  }
}

// zero wp[N] and padded bcnt[256*16]
__global__ void k_init(float* wp, int* bcnt, int N) {
  int i = blockIdx.x * 256 + threadIdx.x;
  if (i < N) wp[i] = 0.f;
  if (i < 256 * 16) bcnt[i] = 0;
}

// P1: per-bucket edge counts (bucket = c >> 8); global merge to line-padded bcnt
__global__ __launch_bounds__(256) void kb_count(const void* ei, const int* flag,
                                                int* bcnt, int E, int N) {
  __shared__ int hist[256];
  int t = threadIdx.x;
  hist[t] = 0;
  __syncthreads();
  int f = *flag;
  for (int e = blockIdx.x * 256 + t; e < E; e += gridDim.x * 256) {
    int r = edge_at(ei, e, f);
    int c = edge_at(ei, (long long)E + e, f);
    if ((unsigned)r < (unsigned)N && (unsigned)c < (unsigned)N)
      atomicAdd(&hist[c >> 8], 1);
  }
  __syncthreads();
  if (hist[t] > 0) atomicAdd(&bcnt[t * 16], hist[t]);  // 1 line per bucket
}

// P2: scan bucket counts -> bases + cursors (padded); rowptr[N]=total
__global__ void kb_scan(const int* bcnt, int* bbase, int* gcursor, int* rowptr,
                        int NB, int N) {
  __shared__ int tmp[256];
  int t = threadIdx.x;
  int v = (t < NB) ? bcnt[t * 16] : 0;
  tmp[t] = v;
  __syncthreads();
  for (int off = 1; off < 256; off <<= 1) {
    int u = (t >= off) ? tmp[t - off] : 0;
    __syncthreads();
    tmp[t] += u;
    __syncthreads();
  }
  int excl = tmp[t] - v;
  bbase[t] = excl;
  gcursor[t * 16] = excl;
  if (t == 255) rowptr[N] = tmp[255];
}

// P3: bucket-sort edges into pairs[] via LDS staging
__global__ __launch_bounds__(256) void kb_scatter(const void* ei, const int* flag,
                                                  int* gcursor, int2* pairs,
                                                  int E, int N) {
  __shared__ int hist[256], lbase[256], lcur[256], gbl[256], tmp[256];
  __shared__ int2 stage[CHUNK];
  int t = threadIdx.x;
  int e0 = blockIdx.x * CHUNK;
  int f = *flag;
  hist[t] = 0;
  __syncthreads();
  int rr[16], cc[16];
#pragma unroll
  for (int k = 0; k < 16; ++k) {
    int e = e0 + k * 256 + t;
    rr[k] = 0; cc[k] = -1;
    if (e < E) {
      int r = edge_at(ei, e, f);
      int c = edge_at(ei, (long long)E + e, f);
      if ((unsigned)r < (unsigned)N && (unsigned)c < (unsigned)N) {
        rr[k] = r; cc[k] = c;
        atomicAdd(&hist[c >> 8], 1);
      }
    }
  }
  __syncthreads();
  int v = hist[t];
  tmp[t] = v;
  __syncthreads();
  for (int off = 1; off < 256; off <<= 1) {
    int u = (t >= off) ? tmp[t - off] : 0;
    __syncthreads();
    tmp[t] += u;
    __syncthreads();
  }
  lbase[t] = tmp[t] - v;
  lcur[t] = tmp[t] - v;
  if (v > 0) gbl[t] = atomicAdd(&gcursor[t * 16], v);  // 1 line per bucket
  __syncthreads();
#pragma unroll
  for (int k = 0; k < 16; ++k) {
    if (cc[k] >= 0) {
      int b = cc[k] >> 8;
      int pos = atomicAdd(&lcur[b], 1);
      stage[pos] = make_int2(rr[k], cc[k]);
    }
  }
  __syncthreads();
  int n = tmp[255];
  for (int i = t; i < n; i += 256) {
    int2 p = stage[i];
    int b = p.y >> 8;
    pairs[gbl[b] + (i - lbase[b])] = p;
  }
}

// P4: per-bucket CSR build + dinv. 1024 threads/block for latency hiding.
__global__ __launch_bounds__(1024) void kb_csr(const int2* __restrict__ pairs,
                                               const int* __restrict__ bcnt,
                                               const int* __restrict__ bbase,
                                               int* rowptr, int* src,
                                               float* dinv, int N) {
  __shared__ int hist[256], lcur[256], tmp[256];
  int t = threadIdx.x;
  int b = blockIdx.x;
  int node0 = b << 8;
  int nn = min(256, N - node0);
  int base = bbase[b];
  int cnt = bcnt[b * 16];
  if (t < 256) hist[t] = 0;
  __syncthreads();
  for (int j = t; j < cnt; j += 1024)
    atomicAdd(&hist[pairs[base + j].y - node0], 1);
  __syncthreads();
  if (t < 256) tmp[t] = hist[t];
  __syncthreads();
  for (int off = 1; off < 256; off <<= 1) {
    int u = (t < 256 && t >= off) ? tmp[t - off] : 0;
    __syncthreads();
    if (t < 256) tmp[t] += u;
    __syncthreads();
  }
  if (t < 256) {
    int v = hist[t];
    lcur[t] = tmp[t] - v;
    if (t < nn) {
      rowptr[node0 + t] = base + tmp[t] - v;
      dinv[node0 + t] = rsqrtf((float)(v + 1));  // +1 self-loop
    }
  }
  __syncthreads();
  for (int j = t; j < cnt; j += 1024) {
    int2 p = pairs[base + j];
    int pos = atomicAdd(&lcur[p.y - node0], 1);
    src[base + pos] = p.x;
  }
}

// P5: wp[r] += dinv[c] over all edges — full-device grid-stride over pairs
__global__ __launch_bounds__(256) void k_wp(const int2* __restrict__ pairs,
                                            const float* __restrict__ dinv,
                                            float* wp, const int* __restrict__ rowptr,
                                            int N) {
  int T = rowptr[N];
  for (int i = blockIdx.x * 256 + threadIdx.x; i < T; i += gridDim.x * 256) {
    int2 p = pairs[i];
    atomicAdd(&wp[p.x], dinv[p.y]);
  }
}

// ---------------------------------------------------------------- GEMMs
// Cb[r,:] = fp8( dinv[r] * (A[r,:] @ W) ), W fp32 128x128

__global__ __launch_bounds__(256) void k_gemm_f32(const float* __restrict__ A,
                                                  const float* __restrict__ W,
                                                  const float* __restrict__ dinv,
                                                  unsigned* __restrict__ Cb, int N) {
  __shared__ float As[64][128];
  __shared__ float Bs[128][64];
  int tid = threadIdx.x;
  int row0 = blockIdx.x * 64;
  int col0 = blockIdx.y * 64;
  {
    int k4 = tid & 31, m = tid >> 5;
    for (int mm = m; mm < 64; mm += 8) {
      int gr = row0 + mm;
      float4 v = make_float4(0.f, 0.f, 0.f, 0.f);
      if (gr < N) v = ((const float4*)A)[(size_t)gr * 32 + k4];
      *(float4*)&As[mm][k4 * 4] = v;
    }
    int n4 = tid & 15, kr = tid >> 4;
    for (int kk = kr; kk < 128; kk += 16) {
      float4 v = ((const float4*)W)[(size_t)kk * 32 + (col0 >> 2) + n4];
      *(float4*)&Bs[kk][n4 * 4] = v;
    }
  }
  __syncthreads();
  int tx = tid & 15, ty = tid >> 4;
  int m0 = ty * 4, n0 = tx * 4;
  float acc[4][4] = {};
#pragma unroll 8
  for (int k = 0; k < 128; ++k) {
    int kk = (k + ty * 33) & 127;
    float a0 = As[m0 + 0][kk], a1 = As[m0 + 1][kk];
    float a2 = As[m0 + 2][kk], a3 = As[m0 + 3][kk];
    float4 b = *(const float4*)&Bs[kk][n0];
    acc[0][0] += a0 * b.x; acc[0][1] += a0 * b.y; acc[0][2] += a0 * b.z; acc[0][3] += a0 * b.w;
    acc[1][0] += a1 * b.x; acc[1][1] += a1 * b.y; acc[1][2] += a1 * b.z; acc[1][3] += a1 * b.w;
    acc[2][0] += a2 * b.x; acc[2][1] += a2 * b.y; acc[2][2] += a2 * b.z; acc[2][3] += a2 * b.w;
    acc[3][0] += a3 * b.x; acc[3][1] += a3 * b.y; acc[3][2] += a3 * b.z; acc[3][3] += a3 * b.w;
  }
#pragma unroll
  for (int i = 0; i < 4; ++i) {
    int gr = row0 + m0 + i;
    if (gr < N) {
      float s = dinv[gr];
      Cb[(size_t)gr * 32 + ((col0 + n0) >> 2)] =
          fp8pk4(acc[i][0] * s, acc[i][1] * s, acc[i][2] * s, acc[i][3] * s);
    }
  }
}

__global__ __launch_bounds__(256) void k_gemm_fp8(const uint4* __restrict__ Ab,
                                                  const float* __restrict__ W,
                                                  const float* __restrict__ dinv,
                                                  unsigned* __restrict__ Cb, int N) {
  __shared__ float As[64][128];
  __shared__ float Bs[128][64];
  int tid = threadIdx.x;
  int row0 = blockIdx.x * 64;
  int col0 = blockIdx.y * 64;
  {
    int k4 = tid & 7, m = tid >> 3;  // 8 uint4 per 128-ch fp8 row
    for (int mm = m; mm < 64; mm += 32) {
      int gr = row0 + mm;
      uint4 v = make_uint4(0, 0, 0, 0);
      if (gr < N) v = Ab[(size_t)gr * 8 + k4];
      float* d = &As[mm][k4 * 16];
      fp8st4(v.x, d); fp8st4(v.y, d + 4); fp8st4(v.z, d + 8); fp8st4(v.w, d + 12);
    }
    int n4 = tid & 15, kr = tid >> 4;
    for (int kk = kr; kk < 128; kk += 16) {
      float4 v = ((const float4*)W)[(size_t)kk * 32 + (col0 >> 2) + n4];
      *(float4*)&Bs[kk][n4 * 4] = v;
    }
  }
  __syncthreads();
  int tx = tid & 15, ty = tid >> 4;
  int m0 = ty * 4, n0 = tx * 4;
  float acc[4][4] = {};
#pragma unroll 8
  for (int k = 0; k < 128; ++k) {
    int kk = (k + ty * 33) & 127;
    float a0 = As[m0 + 0][kk], a1 = As[m0 + 1][kk];
    float a2 = As[m0 + 2][kk], a3 = As[m0 + 3][kk];
    float4 b = *(const float4*)&Bs[kk][n0];
    acc[0][0] += a0 * b.x; acc[0][1] += a0 * b.y; acc[0][2] += a0 * b.z; acc[0][3] += a0 * b.w;
    acc[1][0] += a1 * b.x; acc[1][1] += a1 * b.y; acc[1][2] += a1 * b.z; acc[1][3] += a1 * b.w;
    acc[2][0] += a2 * b.x; acc[2][1] += a2 * b.y; acc[2][2] += a2 * b.z; acc[2][3] += a2 * b.w;
    acc[3][0] += a3 * b.x; acc[3][1] += a3 * b.y; acc[3][2] += a3 * b.z; acc[3][3] += a3 * b.w;
  }
#pragma unroll
  for (int i = 0; i < 4; ++i) {
    int gr = row0 + m0 + i;
    if (gr < N) {
      float s = dinv[gr];
      Cb[(size_t)gr * 32 + ((col0 + n0) >> 2)] =
          fp8pk4(acc[i][0] * s, acc[i][1] * s, acc[i][2] * s, acc[i][3] * s);
    }
  }
}

// ---------------------------------------------------------------- aggregate (fp8)
// out[c,:] = fp8(relu(dinv[c]*(hh[c,:] + sum_{r} hh[r,:]) + bias))
__global__ __launch_bounds__(256) void k_aggf(const uint4* __restrict__ hh,
                                              const float* __restrict__ dinv,
                                              const int* __restrict__ rowptr,
                                              const int* __restrict__ src,
                                              const float* __restrict__ bias,
                                              uint4* __restrict__ outb, int N) {
  int tx = threadIdx.x;  // 0..7 : 16-channel chunk
  int ty = threadIdx.y;  // 0..31: node slot
  float bv[16];
#pragma unroll
  for (int i = 0; i < 16; ++i) bv[i] = bias[tx * 16 + i];

  for (int c = blockIdx.x * 32 + ty; c < N; c += gridDim.x * 32) {
    float acc[16] = {};
    fp8acc16(hh[(size_t)c * 8 + tx], acc);  // self-loop
    int j = rowptr[c], je = rowptr[c + 1];
    for (; j + 8 <= je; j += 8) {
      int r0 = src[j + 0], r1 = src[j + 1], r2 = src[j + 2], r3 = src[j + 3];
      int r4 = src[j + 4], r5 = src[j + 5], r6 = src[j + 6], r7 = src[j + 7];
      uint4 v0 = hh[(size_t)r0 * 8 + tx];
      uint4 v1 = hh[(size_t)r1 * 8 + tx];
      uint4 v2 = hh[(size_t)r2 * 8 + tx];
      uint4 v3 = hh[(size_t)r3 * 8 + tx];
      uint4 v4 = hh[(size_t)r4 * 8 + tx];
      uint4 v5 = hh[(size_t)r5 * 8 + tx];
      uint4 v6 = hh[(size_t)r6 * 8 + tx];
      uint4 v7 = hh[(size_t)r7 * 8 + tx];
      fp8acc16(v0, acc); fp8acc16(v1, acc); fp8acc16(v2, acc); fp8acc16(v3, acc);
      fp8acc16(v4, acc); fp8acc16(v5, acc); fp8acc16(v6, acc); fp8acc16(v7, acc);
    }
    for (; j < je; ++j) fp8acc16(hh[(size_t)src[j] * 8 + tx], acc);
    float s = dinv[c];
    float o[16];
#pragma unroll
    for (int i = 0; i < 16; ++i) o[i] = fmaxf(acc[i] * s + bv[i], 0.f);
    uint4 ov;
    ov.x = fp8pk4(o[0], o[1], o[2], o[3]);
    ov.y = fp8pk4(o[4], o[5], o[6], o[7]);
    ov.z = fp8pk4(o[8], o[9], o[10], o[11]);
    ov.w = fp8pk4(o[12], o[13], o[14], o[15]);
    outb[(size_t)c * 8 + tx] = ov;
  }
}

// ---------------------------------------------------------------- layer-3 collapse
// partial[b][ch] = sum over this block's c of (dinv[c]+wp[c])*dinv[c]*xb[c,ch]
// NO global atomics (device-atomics to few lines serialize ~25ns/instr — R6).
__global__ __launch_bounds__(256) void k_usumf(const uint4* __restrict__ xb,
                                               const float* __restrict__ wp,
                                               const float* __restrict__ dinv,
                                               float* __restrict__ partial, int N) {
  __shared__ float red[32][129];  // stride 129: 4-way max bank aliasing
  int tx = threadIdx.x;  // 0..7
  int ty = threadIdx.y;  // 0..31
  float acc[16] = {};
  for (int c = blockIdx.x * 32 + ty; c < N; c += gridDim.x * 32) {
    float d = dinv[c];
    float wt = (d + wp[c]) * d;
    uint4 v = xb[(size_t)c * 8 + tx];
    fp8wacc4(v.x, wt, acc); fp8wacc4(v.y, wt, acc + 4);
    fp8wacc4(v.z, wt, acc + 8); fp8wacc4(v.w, wt, acc + 12);
  }
#pragma unroll
  for (int i = 0; i < 16; ++i) red[ty][tx * 16 + i] = acc[i];
  __syncthreads();
  for (int s = 16; s > 0; s >>= 1) {
    if (ty < s) {
#pragma unroll
      for (int i = 0; i < 16; ++i) red[ty][tx * 16 + i] += red[ty + s][tx * 16 + i];
    }
    __syncthreads();
  }
  if (ty == 0) {
#pragma unroll
    for (int i = 0; i < 16; ++i)
      partial[(size_t)blockIdx.x * CH + tx * 16 + i] = red[0][tx * 16 + i];
  }
}

// ---------------------------------------------------------------- epilogue
// u = reduce(partial); S=(u/N)@W3; g=S+b3; out=sigmoid(g.Wl+bl)
__global__ void k_final(const float* __restrict__ partial, int nb,
                        const float* __restrict__ W3, const float* __restrict__ b3,
                        const float* __restrict__ Wl, const float* __restrict__ bl,
                        float* __restrict__ out, float invN) {
  __shared__ float us[CH];
  __shared__ float red[CH];
  int t = threadIdx.x;
  float u = 0.f;
  for (int b = 0; b < nb; ++b) u += partial[(size_t)b * CH + t];
  us[t] = u * invN;
  __syncthreads();
  float s = 0.f;
  for (int k = 0; k < CH; ++k) s += us[k] * W3[(size_t)k * CH + t];
  float g = s + b3[t];
  red[t] = g * Wl[t];
  __syncthreads();
  for (int off = 64; off > 0; off >>= 1) {
    if (t < off) red[t] += red[t + off];
    __syncthreads();
  }
  if (t == 0) out[0] = 1.f / (1.f + expf(-(red[0] + bl[0])));
}

// ---------------------------------------------------------------- launch

extern "C" void kernel_launch(void* const* d_in, const int* in_sizes, int n_in,
                              void* d_out, int out_size, void* d_ws, size_t ws_size,
                              hipStream_t stream) {
  const float* x  = (const float*)d_in[0];
  const void*  ei = d_in[1];
  const float* W1 = (const float*)d_in[3];
  const float* b1 = (const float*)d_in[4];
  const float* W2 = (const float*)d_in[5];
  const float* b2 = (const float*)d_in[6];
  const float* W3 = (const float*)d_in[7];
  const float* b3 = (const float*)d_in[8];
  const float* Wl = (const float*)d_in[9];
  const float* bl = (const float*)d_in[10];
  float* out = (float*)d_out;

  const int N = in_sizes[0] / CH;
  const int E = in_sizes[1] / 2;
  const int NB = (N + 255) >> 8;

  char* ws = (char*)d_ws;
  size_t off = 0;
  auto alloc = [&](size_t bytes) -> void* {
    void* p = ws + off;
    off += (bytes + 511) & ~(size_t)511;
    return p;
  };
  int*   flag   = (int*)alloc(4);
  float* dinv   = (float*)alloc((size_t)N * 4);
  float* wp     = (float*)alloc((size_t)N * 4);
  int*   rowptr = (int*)alloc((size_t)(N + 1) * 4);
  int*   bcnt   = (int*)alloc(256 * 16 * 4);  // line-padded: 1 bucket / 64B
  int*   bbase  = (int*)alloc(256 * 4);
  int*   gcur   = (int*)alloc(256 * 16 * 4);  // line-padded
  float* part   = (float*)alloc((size_t)NBU * CH * 4);
  int*   src    = (int*)alloc((size_t)E * 4);
  int2*  pairs  = (int2*)alloc((size_t)E * 8);
  uint4* hbuf   = (uint4*)alloc((size_t)N * CH);  // fp8 rows (128 B)
  uint4* xbuf   = (uint4*)alloc((size_t)N * CH);  // fp8 rows

  const int nbN = (N + 255) / 256;
  const int nbE = (E + 255) / 256;
  const int nCk = (E + CHUNK - 1) / CHUNK;

  // ---- preprocessing: bucket CSR + dinv + wp
  k_detect<<<1, 64, 0, stream>>>((const int*)ei, flag);
  k_init<<<nbN, 256, 0, stream>>>(wp, bcnt, N);
  kb_count<<<nCk, 256, 0, stream>>>(ei, flag, bcnt, E, N);
  kb_scan<<<1, 256, 0, stream>>>(bcnt, bbase, gcur, rowptr, NB, N);
  kb_scatter<<<nCk, 256, 0, stream>>>(ei, flag, gcur, pairs, E, N);
  kb_csr<<<NB, 1024, 0, stream>>>(pairs, bcnt, bbase, rowptr, src, dinv, N);
  k_wp<<<nbE, 256, 0, stream>>>(pairs, dinv, wp, rowptr, N);

  // ---- layers 1 & 2
  dim3 ggrid((N + 63) / 64, 2);
  dim3 ablk(8, 32);
  dim3 agrid((N + 31) / 32);

  k_gemm_f32<<<ggrid, 256, 0, stream>>>(x, W1, dinv, (unsigned*)hbuf, N);
  k_aggf<<<agrid, ablk, 0, stream>>>(hbuf, dinv, rowptr, src, b1, xbuf, N);
  k_gemm_fp8<<<ggrid, 256, 0, stream>>>(xbuf, W2, dinv, (unsigned*)hbuf, N);
  k_aggf<<<agrid, ablk, 0, stream>>>(hbuf, dinv, rowptr, src, b2, xbuf, N);

  // ---- layer 3 collapsed: per-block partials, no hot-line atomics
  k_usumf<<<NBU, ablk, 0, stream>>>(xbuf, wp, dinv, part, N);
  k_final<<<1, CH, 0, stream>>>(part, NBU, W3, b3, Wl, bl, out, 1.0f / (float)N);
}

// Round 8
// 458.639 us; speedup vs baseline: 1.0979x; 1.0151x over previous
//
#include <hip/hip_runtime.h>

#define CH 128
#define CHUNK 4096
#define NBU 256   // k_usumf grid
#define NWP 8     // wp partial shards (XCD proxy)

typedef float v2f __attribute__((ext_vector_type(2)));

// ---------------------------------------------------------------- fp8 helpers (OCP e4m3)

__device__ __forceinline__ void fp8acc4(unsigned w, float* a) {
  v2f p0 = __builtin_amdgcn_cvt_pk_f32_fp8(w, false);
  v2f p1 = __builtin_amdgcn_cvt_pk_f32_fp8(w, true);
  a[0] += p0.x; a[1] += p0.y; a[2] += p1.x; a[3] += p1.y;
}
__device__ __forceinline__ void fp8acc16(uint4 v, float* a) {
  fp8acc4(v.x, a); fp8acc4(v.y, a + 4); fp8acc4(v.z, a + 8); fp8acc4(v.w, a + 12);
}
__device__ __forceinline__ void fp8wacc4(unsigned w, float wt, float* a) {
  v2f p0 = __builtin_amdgcn_cvt_pk_f32_fp8(w, false);
  v2f p1 = __builtin_amdgcn_cvt_pk_f32_fp8(w, true);
  a[0] += wt * p0.x; a[1] += wt * p0.y; a[2] += wt * p1.x; a[3] += wt * p1.y;
}
__device__ __forceinline__ void fp8st4(unsigned w, float* d) {
  v2f p0 = __builtin_amdgcn_cvt_pk_f32_fp8(w, false);
  v2f p1 = __builtin_amdgcn_cvt_pk_f32_fp8(w, true);
  d[0] = p0.x; d[1] = p0.y; d[2] = p1.x; d[3] = p1.y;
}
__device__ __forceinline__ unsigned fp8pk4(float a, float b, float c, float d) {
  int w = 0;
  w = __builtin_amdgcn_cvt_pk_fp8_f32(a, b, w, false);
  w = __builtin_amdgcn_cvt_pk_fp8_f32(c, d, w, true);
  return (unsigned)w;
}

// ---------------------------------------------------------------- utilities

__device__ __forceinline__ int edge_at(const void* ei, long long i, int is64) {
  if (is64) return (int)((const long long*)ei)[i];
  return ((const int*)ei)[i];
}

__global__ void k_detect(const int* ei, int* flag) {
  if (blockIdx.x == 0 && threadIdx.x == 0) {
    int is64 = 1;
    for (int k = 1; k < 128; k += 2)
      if (ei[k] != 0) { is64 = 0; break; }
    *flag = is64;
  }
}

// zero wpp[NWP*N] and padded bcnt[256*16]
__global__ void k_init(float* wpp, int* bcnt, int total) {
  int i = blockIdx.x * 256 + threadIdx.x;
  if (i < total) wpp[i] = 0.f;
  if (i < 256 * 16) bcnt[i] = 0;
}

// P1: per-bucket edge counts (bucket = c >> 8); global merge to line-padded bcnt
__global__ __launch_bounds__(256) void kb_count(const void* ei, const int* flag,
                                                int* bcnt, int E, int N) {
  __shared__ int hist[256];
  int t = threadIdx.x;
  hist[t] = 0;
  __syncthreads();
  int f = *flag;
  for (int e = blockIdx.x * 256 + t; e < E; e += gridDim.x * 256) {
    int r = edge_at(ei, e, f);
    int c = edge_at(ei, (long long)E + e, f);
    if ((unsigned)r < (unsigned)N && (unsigned)c < (unsigned)N)
      atomicAdd(&hist[c >> 8], 1);
  }
  __syncthreads();
  if (hist[t] > 0) atomicAdd(&bcnt[t * 16], hist[t]);  // 1 line per bucket
}

// P2: scan bucket counts -> bases + cursors (padded); rowptr[N]=total
__global__ void kb_scan(const int* bcnt, int* bbase, int* gcursor, int* rowptr,
                        int NB, int N) {
  __shared__ int tmp[256];
  int t = threadIdx.x;
  int v = (t < NB) ? bcnt[t * 16] : 0;
  tmp[t] = v;
  __syncthreads();
  for (int off = 1; off < 256; off <<= 1) {
    int u = (t >= off) ? tmp[t - off] : 0;
    __syncthreads();
    tmp[t] += u;
    __syncthreads();
  }
  int excl = tmp[t] - v;
  bbase[t] = excl;
  gcursor[t * 16] = excl;
  if (t == 255) rowptr[N] = tmp[255];
}

// P3: bucket-sort edges into pairs[] via LDS staging
__global__ __launch_bounds__(256) void kb_scatter(const void* ei, const int* flag,
                                                  int* gcursor, int2* pairs,
                                                  int E, int N) {
  __shared__ int hist[256], lbase[256], lcur[256], gbl[256], tmp[256];
  __shared__ int2 stage[CHUNK];
  int t = threadIdx.x;
  int e0 = blockIdx.x * CHUNK;
  int f = *flag;
  hist[t] = 0;
  __syncthreads();
  int rr[16], cc[16];
#pragma unroll
  for (int k = 0; k < 16; ++k) {
    int e = e0 + k * 256 + t;
    rr[k] = 0; cc[k] = -1;
    if (e < E) {
      int r = edge_at(ei, e, f);
      int c = edge_at(ei, (long long)E + e, f);
      if ((unsigned)r < (unsigned)N && (unsigned)c < (unsigned)N) {
        rr[k] = r; cc[k] = c;
        atomicAdd(&hist[c >> 8], 1);
      }
    }
  }
  __syncthreads();
  int v = hist[t];
  tmp[t] = v;
  __syncthreads();
  for (int off = 1; off < 256; off <<= 1) {
    int u = (t >= off) ? tmp[t - off] : 0;
    __syncthreads();
    tmp[t] += u;
    __syncthreads();
  }
  lbase[t] = tmp[t] - v;
  lcur[t] = tmp[t] - v;
  if (v > 0) gbl[t] = atomicAdd(&gcursor[t * 16], v);  // 1 line per bucket
  __syncthreads();
#pragma unroll
  for (int k = 0; k < 16; ++k) {
    if (cc[k] >= 0) {
      int b = cc[k] >> 8;
      int pos = atomicAdd(&lcur[b], 1);
      stage[pos] = make_int2(rr[k], cc[k]);
    }
  }
  __syncthreads();
  int n = tmp[255];
  for (int i = t; i < n; i += 256) {
    int2 p = stage[i];
    int b = p.y >> 8;
    pairs[gbl[b] + (i - lbase[b])] = p;
  }
}

// P4: per-bucket CSR build + dinv. 1024 threads/block for latency hiding.
__global__ __launch_bounds__(1024) void kb_csr(const int2* __restrict__ pairs,
                                               const int* __restrict__ bcnt,
                                               const int* __restrict__ bbase,
                                               int* rowptr, int* src,
                                               float* dinv, int N) {
  __shared__ int hist[256], lcur[256], tmp[256];
  int t = threadIdx.x;
  int b = blockIdx.x;
  int node0 = b << 8;
  int nn = min(256, N - node0);
  int base = bbase[b];
  int cnt = bcnt[b * 16];
  if (t < 256) hist[t] = 0;
  __syncthreads();
  for (int j = t; j < cnt; j += 1024)
    atomicAdd(&hist[pairs[base + j].y - node0], 1);
  __syncthreads();
  if (t < 256) tmp[t] = hist[t];
  __syncthreads();
  for (int off = 1; off < 256; off <<= 1) {
    int u = (t < 256 && t >= off) ? tmp[t - off] : 0;
    __syncthreads();
    if (t < 256) tmp[t] += u;
    __syncthreads();
  }
  if (t < 256) {
    int v = hist[t];
    lcur[t] = tmp[t] - v;
    if (t < nn) {
      rowptr[node0 + t] = base + tmp[t] - v;
      dinv[node0 + t] = rsqrtf((float)(v + 1));  // +1 self-loop
    }
  }
  __syncthreads();
  for (int j = t; j < cnt; j += 1024) {
    int2 p = pairs[base + j];
    int pos = atomicAdd(&lcur[p.y - node0], 1);
    src[base + pos] = p.x;
  }
}

// P5: wpp[blk&7][r] += dinv[c] — sharded partials kill cross-XCD line bounce
__global__ __launch_bounds__(256) void k_wp(const int2* __restrict__ pairs,
                                            const float* __restrict__ dinv,
                                            float* wpp, const int* __restrict__ rowptr,
                                            int N) {
  int T = rowptr[N];
  float* mine = wpp + (size_t)(blockIdx.x & (NWP - 1)) * N;
  for (int i = blockIdx.x * 256 + threadIdx.x; i < T; i += gridDim.x * 256) {
    int2 p = pairs[i];
    atomicAdd(&mine[p.x], dinv[p.y]);
  }
}

// P6: wp[i] = sum_k wpp[k][i]
__global__ void k_wred(const float* __restrict__ wpp, float* __restrict__ wp, int N) {
  int i = blockIdx.x * 256 + threadIdx.x;
  if (i >= N) return;
  float s = 0.f;
#pragma unroll
  for (int k = 0; k < NWP; ++k) s += wpp[(size_t)k * N + i];
  wp[i] = s;
}

// ---------------------------------------------------------------- GEMMs
// Cb[r,:] = fp8( dinv[r] * (A[r,:] @ W) ), W fp32 128x128

__global__ __launch_bounds__(256) void k_gemm_f32(const float* __restrict__ A,
                                                  const float* __restrict__ W,
                                                  const float* __restrict__ dinv,
                                                  unsigned* __restrict__ Cb, int N) {
  __shared__ float As[64][128];
  __shared__ float Bs[128][64];
  int tid = threadIdx.x;
  int row0 = blockIdx.x * 64;
  int col0 = blockIdx.y * 64;
  {
    int k4 = tid & 31, m = tid >> 5;
    for (int mm = m; mm < 64; mm += 8) {
      int gr = row0 + mm;
      float4 v = make_float4(0.f, 0.f, 0.f, 0.f);
      if (gr < N) v = ((const float4*)A)[(size_t)gr * 32 + k4];
      *(float4*)&As[mm][k4 * 4] = v;
    }
    int n4 = tid & 15, kr = tid >> 4;
    for (int kk = kr; kk < 128; kk += 16) {
      float4 v = ((const float4*)W)[(size_t)kk * 32 + (col0 >> 2) + n4];
      *(float4*)&Bs[kk][n4 * 4] = v;
    }
  }
  __syncthreads();
  int tx = tid & 15, ty = tid >> 4;
  int m0 = ty * 4, n0 = tx * 4;
  float acc[4][4] = {};
#pragma unroll 8
  for (int k = 0; k < 128; ++k) {
    int kk = (k + ty * 33) & 127;
    float a0 = As[m0 + 0][kk], a1 = As[m0 + 1][kk];
    float a2 = As[m0 + 2][kk], a3 = As[m0 + 3][kk];
    float4 b = *(const float4*)&Bs[kk][n0];
    acc[0][0] += a0 * b.x; acc[0][1] += a0 * b.y; acc[0][2] += a0 * b.z; acc[0][3] += a0 * b.w;
    acc[1][0] += a1 * b.x; acc[1][1] += a1 * b.y; acc[1][2] += a1 * b.z; acc[1][3] += a1 * b.w;
    acc[2][0] += a2 * b.x; acc[2][1] += a2 * b.y; acc[2][2] += a2 * b.z; acc[2][3] += a2 * b.w;
    acc[3][0] += a3 * b.x; acc[3][1] += a3 * b.y; acc[3][2] += a3 * b.z; acc[3][3] += a3 * b.w;
  }
#pragma unroll
  for (int i = 0; i < 4; ++i) {
    int gr = row0 + m0 + i;
    if (gr < N) {
      float s = dinv[gr];
      Cb[(size_t)gr * 32 + ((col0 + n0) >> 2)] =
          fp8pk4(acc[i][0] * s, acc[i][1] * s, acc[i][2] * s, acc[i][3] * s);
    }
  }
}

__global__ __launch_bounds__(256) void k_gemm_fp8(const uint4* __restrict__ Ab,
                                                  const float* __restrict__ W,
                                                  const float* __restrict__ dinv,
                                                  unsigned* __restrict__ Cb, int N) {
  __shared__ float As[64][128];
  __shared__ float Bs[128][64];
  int tid = threadIdx.x;
  int row0 = blockIdx.x * 64;
  int col0 = blockIdx.y * 64;
  {
    int k4 = tid & 7, m = tid >> 3;  // 8 uint4 per 128-ch fp8 row
    for (int mm = m; mm < 64; mm += 32) {
      int gr = row0 + mm;
      uint4 v = make_uint4(0, 0, 0, 0);
      if (gr < N) v = Ab[(size_t)gr * 8 + k4];
      float* d = &As[mm][k4 * 16];
      fp8st4(v.x, d); fp8st4(v.y, d + 4); fp8st4(v.z, d + 8); fp8st4(v.w, d + 12);
    }
    int n4 = tid & 15, kr = tid >> 4;
    for (int kk = kr; kk < 128; kk += 16) {
      float4 v = ((const float4*)W)[(size_t)kk * 32 + (col0 >> 2) + n4];
      *(float4*)&Bs[kk][n4 * 4] = v;
    }
  }
  __syncthreads();
  int tx = tid & 15, ty = tid >> 4;
  int m0 = ty * 4, n0 = tx * 4;
  float acc[4][4] = {};
#pragma unroll 8
  for (int k = 0; k < 128; ++k) {
    int kk = (k + ty * 33) & 127;
    float a0 = As[m0 + 0][kk], a1 = As[m0 + 1][kk];
    float a2 = As[m0 + 2][kk], a3 = As[m0 + 3][kk];
    float4 b = *(const float4*)&Bs[kk][n0];
    acc[0][0] += a0 * b.x; acc[0][1] += a0 * b.y; acc[0][2] += a0 * b.z; acc[0][3] += a0 * b.w;
    acc[1][0] += a1 * b.x; acc[1][1] += a1 * b.y; acc[1][2] += a1 * b.z; acc[1][3] += a1 * b.w;
    acc[2][0] += a2 * b.x; acc[2][1] += a2 * b.y; acc[2][2] += a2 * b.z; acc[2][3] += a2 * b.w;
    acc[3][0] += a3 * b.x; acc[3][1] += a3 * b.y; acc[3][2] += a3 * b.z; acc[3][3] += a3 * b.w;
  }
#pragma unroll
  for (int i = 0; i < 4; ++i) {
    int gr = row0 + m0 + i;
    if (gr < N) {
      float s = dinv[gr];
      Cb[(size_t)gr * 32 + ((col0 + n0) >> 2)] =
          fp8pk4(acc[i][0] * s, acc[i][1] * s, acc[i][2] * s, acc[i][3] * s);
    }
  }
}

// ---------------------------------------------------------------- aggregate (fp8)
// out[c,:] = fp8(relu(dinv[c]*(hh[c,:] + sum_{r} hh[r,:]) + bias))
__global__ __launch_bounds__(256) void k_aggf(const uint4* __restrict__ hh,
                                              const float* __restrict__ dinv,
                                              const int* __restrict__ rowptr,
                                              const int* __restrict__ src,
                                              const float* __restrict__ bias,
                                              uint4* __restrict__ outb, int N) {
  int tx = threadIdx.x;  // 0..7 : 16-channel chunk
  int ty = threadIdx.y;  // 0..31: node slot
  float bv[16];
#pragma unroll
  for (int i = 0; i < 16; ++i) bv[i] = bias[tx * 16 + i];

  for (int c = blockIdx.x * 32 + ty; c < N; c += gridDim.x * 32) {
    float acc[16] = {};
    fp8acc16(hh[(size_t)c * 8 + tx], acc);  // self-loop
    int j = rowptr[c], je = rowptr[c + 1];
    for (; j + 8 <= je; j += 8) {
      int r0 = src[j + 0], r1 = src[j + 1], r2 = src[j + 2], r3 = src[j + 3];
      int r4 = src[j + 4], r5 = src[j + 5], r6 = src[j + 6], r7 = src[j + 7];
      uint4 v0 = hh[(size_t)r0 * 8 + tx];
      uint4 v1 = hh[(size_t)r1 * 8 + tx];
      uint4 v2 = hh[(size_t)r2 * 8 + tx];
      uint4 v3 = hh[(size_t)r3 * 8 + tx];
      uint4 v4 = hh[(size_t)r4 * 8 + tx];
      uint4 v5 = hh[(size_t)r5 * 8 + tx];
      uint4 v6 = hh[(size_t)r6 * 8 + tx];
      uint4 v7 = hh[(size_t)r7 * 8 + tx];
      fp8acc16(v0, acc); fp8acc16(v1, acc); fp8acc16(v2, acc); fp8acc16(v3, acc);
      fp8acc16(v4, acc); fp8acc16(v5, acc); fp8acc16(v6, acc); fp8acc16(v7, acc);
    }
    for (; j < je; ++j) fp8acc16(hh[(size_t)src[j] * 8 + tx], acc);
    float s = dinv[c];
    float o[16];
#pragma unroll
    for (int i = 0; i < 16; ++i) o[i] = fmaxf(acc[i] * s + bv[i], 0.f);
    uint4 ov;
    ov.x = fp8pk4(o[0], o[1], o[2], o[3]);
    ov.y = fp8pk4(o[4], o[5], o[6], o[7]);
    ov.z = fp8pk4(o[8], o[9], o[10], o[11]);
    ov.w = fp8pk4(o[12], o[13], o[14], o[15]);
    outb[(size_t)c * 8 + tx] = ov;
  }
}

// ---------------------------------------------------------------- layer-3 collapse
// partial[b][ch] = sum over this block's c of (dinv[c]+wp[c])*dinv[c]*xb[c,ch]
__global__ __launch_bounds__(256) void k_usumf(const uint4* __restrict__ xb,
                                               const float* __restrict__ wp,
                                               const float* __restrict__ dinv,
                                               float* __restrict__ partial, int N) {
  __shared__ float red[32][129];
  int tx = threadIdx.x;  // 0..7
  int ty = threadIdx.y;  // 0..31
  float acc[16] = {};
  for (int c = blockIdx.x * 32 + ty; c < N; c += gridDim.x * 32) {
    float d = dinv[c];
    float wt = (d + wp[c]) * d;
    uint4 v = xb[(size_t)c * 8 + tx];
    fp8wacc4(v.x, wt, acc); fp8wacc4(v.y, wt, acc + 4);
    fp8wacc4(v.z, wt, acc + 8); fp8wacc4(v.w, wt, acc + 12);
  }
#pragma unroll
  for (int i = 0; i < 16; ++i) red[ty][tx * 16 + i] = acc[i];
  __syncthreads();
  for (int s = 16; s > 0; s >>= 1) {
    if (ty < s) {
#pragma unroll
      for (int i = 0; i < 16; ++i) red[ty][tx * 16 + i] += red[ty + s][tx * 16 + i];
    }
    __syncthreads();
  }
  if (ty == 0) {
#pragma unroll
    for (int i = 0; i < 16; ++i)
      partial[(size_t)blockIdx.x * CH + tx * 16 + i] = red[0][tx * 16 + i];
  }
}

// ---------------------------------------------------------------- epilogue
__global__ void k_final(const float* __restrict__ partial, int nb,
                        const float* __restrict__ W3, const float* __restrict__ b3,
                        const float* __restrict__ Wl, const float* __restrict__ bl,
                        float* __restrict__ out, float invN) {
  __shared__ float us[CH];
  __shared__ float red[CH];
  int t = threadIdx.x;
  float u = 0.f;
  for (int b = 0; b < nb; ++b) u += partial[(size_t)b * CH + t];
  us[t] = u * invN;
  __syncthreads();
  float s = 0.f;
  for (int k = 0; k < CH; ++k) s += us[k] * W3[(size_t)k * CH + t];
  float g = s + b3[t];
  red[t] = g * Wl[t];
  __syncthreads();
  for (int off = 64; off > 0; off >>= 1) {
    if (t < off) red[t] += red[t + off];
    __syncthreads();
  }
  if (t == 0) out[0] = 1.f / (1.f + expf(-(red[0] + bl[0])));
}

// ---------------------------------------------------------------- launch

extern "C" void kernel_launch(void* const* d_in, const int* in_sizes, int n_in,
                              void* d_out, int out_size, void* d_ws, size_t ws_size,
                              hipStream_t stream) {
  const float* x  = (const float*)d_in[0];
  const void*  ei = d_in[1];
  const float* W1 = (const float*)d_in[3];
  const float* b1 = (const float*)d_in[4];
  const float* W2 = (const float*)d_in[5];
  const float* b2 = (const float*)d_in[6];
  const float* W3 = (const float*)d_in[7];
  const float* b3 = (const float*)d_in[8];
  const float* Wl = (const float*)d_in[9];
  const float* bl = (const float*)d_in[10];
  float* out = (float*)d_out;

  const int N = in_sizes[0] / CH;
  const int E = in_sizes[1] / 2;
  const int NB = (N + 255) >> 8;

  char* ws = (char*)d_ws;
  size_t off = 0;
  auto alloc = [&](size_t bytes) -> void* {
    void* p = ws + off;
    off += (bytes + 511) & ~(size_t)511;
    return p;
  };
  int*   flag   = (int*)alloc(4);
  float* dinv   = (float*)alloc((size_t)N * 4);
  float* wp     = (float*)alloc((size_t)N * 4);
  float* wpp    = (float*)alloc((size_t)NWP * N * 4);
  int*   rowptr = (int*)alloc((size_t)(N + 1) * 4);
  int*   bcnt   = (int*)alloc(256 * 16 * 4);
  int*   bbase  = (int*)alloc(256 * 4);
  int*   gcur   = (int*)alloc(256 * 16 * 4);
  float* part   = (float*)alloc((size_t)NBU * CH * 4);
  int*   src    = (int*)alloc((size_t)E * 4);
  int2*  pairs  = (int2*)alloc((size_t)E * 8);
  uint4* hbuf   = (uint4*)alloc((size_t)N * CH);  // fp8 rows (128 B)
  uint4* xbuf   = (uint4*)alloc((size_t)N * CH);  // fp8 rows

  const int nbN = (N + 255) / 256;
  const int nbE = (E + 255) / 256;
  const int nCk = (E + CHUNK - 1) / CHUNK;
  const int nbW = (NWP * N + 255) / 256;

  // ---- preprocessing: bucket CSR + dinv + wp (sharded)
  k_detect<<<1, 64, 0, stream>>>((const int*)ei, flag);
  k_init<<<nbW, 256, 0, stream>>>(wpp, bcnt, NWP * N);
  kb_count<<<nCk, 256, 0, stream>>>(ei, flag, bcnt, E, N);
  kb_scan<<<1, 256, 0, stream>>>(bcnt, bbase, gcur, rowptr, NB, N);
  kb_scatter<<<nCk, 256, 0, stream>>>(ei, flag, gcur, pairs, E, N);
  kb_csr<<<NB, 1024, 0, stream>>>(pairs, bcnt, bbase, rowptr, src, dinv, N);
  k_wp<<<nbE, 256, 0, stream>>>(pairs, dinv, wpp, rowptr, N);
  k_wred<<<nbN, 256, 0, stream>>>(wpp, wp, N);

  // ---- layers 1 & 2
  dim3 ggrid((N + 63) / 64, 2);
  dim3 ablk(8, 32);
  dim3 agrid((N + 31) / 32);

  k_gemm_f32<<<ggrid, 256, 0, stream>>>(x, W1, dinv, (unsigned*)hbuf, N);
  k_aggf<<<agrid, ablk, 0, stream>>>(hbuf, dinv, rowptr, src, b1, xbuf, N);
  k_gemm_fp8<<<ggrid, 256, 0, stream>>>(xbuf, W2, dinv, (unsigned*)hbuf, N);
  k_aggf<<<agrid, ablk, 0, stream>>>(hbuf, dinv, rowptr, src, b2, xbuf, N);

  // ---- layer 3 collapsed
  k_usumf<<<NBU, ablk, 0, stream>>>(xbuf, wp, dinv, part, N);
  k_final<<<1, CH, 0, stream>>>(part, NBU, W3, b3, Wl, bl, out, 1.0f / (float)N);
}

// Round 9
// 427.933 us; speedup vs baseline: 1.1767x; 1.0718x over previous
//
#include <hip/hip_runtime.h>

#define CH 128
#define CHUNK 4096
#define NBU 256   // k_usumf grid

typedef float v2f __attribute__((ext_vector_type(2)));

// ---------------------------------------------------------------- fp8 helpers (OCP e4m3)

__device__ __forceinline__ void fp8acc4(unsigned w, float* a) {
  v2f p0 = __builtin_amdgcn_cvt_pk_f32_fp8(w, false);
  v2f p1 = __builtin_amdgcn_cvt_pk_f32_fp8(w, true);
  a[0] += p0.x; a[1] += p0.y; a[2] += p1.x; a[3] += p1.y;
}
__device__ __forceinline__ void fp8acc16(uint4 v, float* a) {
  fp8acc4(v.x, a); fp8acc4(v.y, a + 4); fp8acc4(v.z, a + 8); fp8acc4(v.w, a + 12);
}
__device__ __forceinline__ void fp8wacc4(unsigned w, float wt, float* a) {
  v2f p0 = __builtin_amdgcn_cvt_pk_f32_fp8(w, false);
  v2f p1 = __builtin_amdgcn_cvt_pk_f32_fp8(w, true);
  a[0] += wt * p0.x; a[1] += wt * p0.y; a[2] += wt * p1.x; a[3] += wt * p1.y;
}
__device__ __forceinline__ void fp8st4(unsigned w, float* d) {
  v2f p0 = __builtin_amdgcn_cvt_pk_f32_fp8(w, false);
  v2f p1 = __builtin_amdgcn_cvt_pk_f32_fp8(w, true);
  d[0] = p0.x; d[1] = p0.y; d[2] = p1.x; d[3] = p1.y;
}
__device__ __forceinline__ unsigned fp8pk4(float a, float b, float c, float d) {
  int w = 0;
  w = __builtin_amdgcn_cvt_pk_fp8_f32(a, b, w, false);
  w = __builtin_amdgcn_cvt_pk_fp8_f32(c, d, w, true);
  return (unsigned)w;
}

// ---------------------------------------------------------------- utilities

__device__ __forceinline__ int edge_at(const void* ei, long long i, int is64) {
  if (is64) return (int)((const long long*)ei)[i];
  return ((const int*)ei)[i];
}

__global__ void k_detect(const int* ei, int* flag) {
  if (blockIdx.x == 0 && threadIdx.x == 0) {
    int is64 = 1;
    for (int k = 1; k < 128; k += 2)
      if (ei[k] != 0) { is64 = 0; break; }
    *flag = is64;
  }
}

// zero padded bcnt[256*16] and rcnt[256*16]
__global__ void k_init(int* bcnt, int* rcnt) {
  int i = blockIdx.x * 256 + threadIdx.x;
  if (i < 256 * 16) { bcnt[i] = 0; rcnt[i] = 0; }
}

// P1: per-bucket edge counts for BOTH c-buckets and r-buckets
__global__ __launch_bounds__(256) void kb_count(const void* ei, const int* flag,
                                                int* bcnt, int* rcnt, int E, int N) {
  __shared__ int hist[256], rhist[256];
  int t = threadIdx.x;
  hist[t] = 0; rhist[t] = 0;
  __syncthreads();
  int f = *flag;
  for (int e = blockIdx.x * 256 + t; e < E; e += gridDim.x * 256) {
    int r = edge_at(ei, e, f);
    int c = edge_at(ei, (long long)E + e, f);
    if ((unsigned)r < (unsigned)N && (unsigned)c < (unsigned)N) {
      atomicAdd(&hist[c >> 8], 1);
      atomicAdd(&rhist[r >> 8], 1);
    }
  }
  __syncthreads();
  if (hist[t] > 0) atomicAdd(&bcnt[t * 16], hist[t]);
  if (rhist[t] > 0) atomicAdd(&rcnt[t * 16], rhist[t]);
}

// P2: scan both bucket-count arrays -> bases + cursors; rowptr[N]=total
__global__ void kb_scan(const int* bcnt, int* bbase, int* gcursor,
                        const int* rcnt, int* rbase, int* rcursor,
                        int* rowptr, int NB, int N) {
  __shared__ int tmp[256];
  int t = threadIdx.x;
  // scan c-buckets
  int v = (t < NB) ? bcnt[t * 16] : 0;
  tmp[t] = v;
  __syncthreads();
  for (int off = 1; off < 256; off <<= 1) {
    int u = (t >= off) ? tmp[t - off] : 0;
    __syncthreads();
    tmp[t] += u;
    __syncthreads();
  }
  bbase[t] = tmp[t] - v;
  gcursor[t * 16] = tmp[t] - v;
  if (t == 255) rowptr[N] = tmp[255];
  __syncthreads();
  // scan r-buckets
  int rv = (t < NB) ? rcnt[t * 16] : 0;
  tmp[t] = rv;
  __syncthreads();
  for (int off = 1; off < 256; off <<= 1) {
    int u = (t >= off) ? tmp[t - off] : 0;
    __syncthreads();
    tmp[t] += u;
    __syncthreads();
  }
  rbase[t] = tmp[t] - rv;
  rcursor[t * 16] = tmp[t] - rv;
}

// P3: bucket-sort edges by KEY into dst[] via LDS staging.
// KEYSEL=0: key=c (store (r,c)); KEYSEL=1: key=r (store (r,c)).
template <int KEYSEL>
__global__ __launch_bounds__(256) void kb_scatter(const void* ei, const int* flag,
                                                  int* gcursor, int2* dst,
                                                  int E, int N) {
  __shared__ int hist[256], lbase[256], lcur[256], gbl[256], tmp[256];
  __shared__ int2 stage[CHUNK];
  int t = threadIdx.x;
  int e0 = blockIdx.x * CHUNK;
  int f = *flag;
  hist[t] = 0;
  __syncthreads();
  int rr[16], cc[16];
#pragma unroll
  for (int k = 0; k < 16; ++k) {
    int e = e0 + k * 256 + t;
    rr[k] = 0; cc[k] = -1;
    if (e < E) {
      int r = edge_at(ei, e, f);
      int c = edge_at(ei, (long long)E + e, f);
      if ((unsigned)r < (unsigned)N && (unsigned)c < (unsigned)N) {
        rr[k] = r; cc[k] = c;
        int key = KEYSEL ? r : c;
        atomicAdd(&hist[key >> 8], 1);
      }
    }
  }
  __syncthreads();
  int v = hist[t];
  tmp[t] = v;
  __syncthreads();
  for (int off = 1; off < 256; off <<= 1) {
    int u = (t >= off) ? tmp[t - off] : 0;
    __syncthreads();
    tmp[t] += u;
    __syncthreads();
  }
  lbase[t] = tmp[t] - v;
  lcur[t] = tmp[t] - v;
  if (v > 0) gbl[t] = atomicAdd(&gcursor[t * 16], v);
  __syncthreads();
#pragma unroll
  for (int k = 0; k < 16; ++k) {
    if (cc[k] >= 0) {
      int key = KEYSEL ? rr[k] : cc[k];
      int b = key >> 8;
      int pos = atomicAdd(&lcur[b], 1);
      stage[pos] = make_int2(rr[k], cc[k]);
    }
  }
  __syncthreads();
  int n = tmp[255];
  for (int i = t; i < n; i += 256) {
    int2 p = stage[i];
    int key = KEYSEL ? p.x : p.y;
    int b = key >> 8;
    dst[gbl[b] + (i - lbase[b])] = p;
  }
}

// P4: per-bucket CSR build + dinv. 1024 threads/block.
__global__ __launch_bounds__(1024) void kb_csr(const int2* __restrict__ pairs,
                                               const int* __restrict__ bcnt,
                                               const int* __restrict__ bbase,
                                               int* rowptr, int* src,
                                               float* dinv, int N) {
  __shared__ int hist[256], lcur[256], tmp[256];
  int t = threadIdx.x;
  int b = blockIdx.x;
  int node0 = b << 8;
  int nn = min(256, N - node0);
  int base = bbase[b];
  int cnt = bcnt[b * 16];
  if (t < 256) hist[t] = 0;
  __syncthreads();
  for (int j = t; j < cnt; j += 1024)
    atomicAdd(&hist[pairs[base + j].y - node0], 1);
  __syncthreads();
  if (t < 256) tmp[t] = hist[t];
  __syncthreads();
  for (int off = 1; off < 256; off <<= 1) {
    int u = (t < 256 && t >= off) ? tmp[t - off] : 0;
    __syncthreads();
    if (t < 256) tmp[t] += u;
    __syncthreads();
  }
  if (t < 256) {
    int v = hist[t];
    lcur[t] = tmp[t] - v;
    if (t < nn) {
      rowptr[node0 + t] = base + tmp[t] - v;
      dinv[node0 + t] = rsqrtf((float)(v + 1));  // +1 self-loop
    }
  }
  __syncthreads();
  for (int j = t; j < cnt; j += 1024) {
    int2 p = pairs[base + j];
    int pos = atomicAdd(&lcur[p.y - node0], 1);
    src[base + pos] = p.x;
  }
}

// P5: wp accumulation from r-sorted pairs — LDS atomics only, no global atomics
// (R8 lesson: scattered device atomics are fabric/IC-bound, ~50ns each).
__global__ __launch_bounds__(1024) void kb_wp(const int2* __restrict__ rpairs,
                                              const int* __restrict__ rcnt,
                                              const int* __restrict__ rbase,
                                              const float* __restrict__ dinv,
                                              float* __restrict__ wp, int N) {
  __shared__ float wpl[256];
  int t = threadIdx.x;
  int b = blockIdx.x;
  int node0 = b << 8;
  int nn = min(256, N - node0);
  int base = rbase[b];
  int cnt = rcnt[b * 16];
  if (t < 256) wpl[t] = 0.f;
  __syncthreads();
  for (int j = t; j < cnt; j += 1024) {
    int2 p = rpairs[base + j];
    atomicAdd(&wpl[p.x - node0], dinv[p.y]);
  }
  __syncthreads();
  if (t < nn) wp[node0 + t] = wpl[t];
}

// ---------------------------------------------------------------- GEMMs
// Cb[r,:] = fp8( dinv[r] * (A[r,:] @ W) ), W fp32 128x128

__global__ __launch_bounds__(256) void k_gemm_f32(const float* __restrict__ A,
                                                  const float* __restrict__ W,
                                                  const float* __restrict__ dinv,
                                                  unsigned* __restrict__ Cb, int N) {
  __shared__ float As[64][128];
  __shared__ float Bs[128][64];
  int tid = threadIdx.x;
  int row0 = blockIdx.x * 64;
  int col0 = blockIdx.y * 64;
  {
    int k4 = tid & 31, m = tid >> 5;
    for (int mm = m; mm < 64; mm += 8) {
      int gr = row0 + mm;
      float4 v = make_float4(0.f, 0.f, 0.f, 0.f);
      if (gr < N) v = ((const float4*)A)[(size_t)gr * 32 + k4];
      *(float4*)&As[mm][k4 * 4] = v;
    }
    int n4 = tid & 15, kr = tid >> 4;
    for (int kk = kr; kk < 128; kk += 16) {
      float4 v = ((const float4*)W)[(size_t)kk * 32 + (col0 >> 2) + n4];
      *(float4*)&Bs[kk][n4 * 4] = v;
    }
  }
  __syncthreads();
  int tx = tid & 15, ty = tid >> 4;
  int m0 = ty * 4, n0 = tx * 4;
  float acc[4][4] = {};
#pragma unroll 8
  for (int k = 0; k < 128; ++k) {
    int kk = (k + ty * 33) & 127;
    float a0 = As[m0 + 0][kk], a1 = As[m0 + 1][kk];
    float a2 = As[m0 + 2][kk], a3 = As[m0 + 3][kk];
    float4 b = *(const float4*)&Bs[kk][n0];
    acc[0][0] += a0 * b.x; acc[0][1] += a0 * b.y; acc[0][2] += a0 * b.z; acc[0][3] += a0 * b.w;
    acc[1][0] += a1 * b.x; acc[1][1] += a1 * b.y; acc[1][2] += a1 * b.z; acc[1][3] += a1 * b.w;
    acc[2][0] += a2 * b.x; acc[2][1] += a2 * b.y; acc[2][2] += a2 * b.z; acc[2][3] += a2 * b.w;
    acc[3][0] += a3 * b.x; acc[3][1] += a3 * b.y; acc[3][2] += a3 * b.z; acc[3][3] += a3 * b.w;
  }
#pragma unroll
  for (int i = 0; i < 4; ++i) {
    int gr = row0 + m0 + i;
    if (gr < N) {
      float s = dinv[gr];
      Cb[(size_t)gr * 32 + ((col0 + n0) >> 2)] =
          fp8pk4(acc[i][0] * s, acc[i][1] * s, acc[i][2] * s, acc[i][3] * s);
    }
  }
}

__global__ __launch_bounds__(256) void k_gemm_fp8(const uint4* __restrict__ Ab,
                                                  const float* __restrict__ W,
                                                  const float* __restrict__ dinv,
                                                  unsigned* __restrict__ Cb, int N) {
  __shared__ float As[64][128];
  __shared__ float Bs[128][64];
  int tid = threadIdx.x;
  int row0 = blockIdx.x * 64;
  int col0 = blockIdx.y * 64;
  {
    int k4 = tid & 7, m = tid >> 3;  // 8 uint4 per 128-ch fp8 row
    for (int mm = m; mm < 64; mm += 32) {
      int gr = row0 + mm;
      uint4 v = make_uint4(0, 0, 0, 0);
      if (gr < N) v = Ab[(size_t)gr * 8 + k4];
      float* d = &As[mm][k4 * 16];
      fp8st4(v.x, d); fp8st4(v.y, d + 4); fp8st4(v.z, d + 8); fp8st4(v.w, d + 12);
    }
    int n4 = tid & 15, kr = tid >> 4;
    for (int kk = kr; kk < 128; kk += 16) {
      float4 v = ((const float4*)W)[(size_t)kk * 32 + (col0 >> 2) + n4];
      *(float4*)&Bs[kk][n4 * 4] = v;
    }
  }
  __syncthreads();
  int tx = tid & 15, ty = tid >> 4;
  int m0 = ty * 4, n0 = tx * 4;
  float acc[4][4] = {};
#pragma unroll 8
  for (int k = 0; k < 128; ++k) {
    int kk = (k + ty * 33) & 127;
    float a0 = As[m0 + 0][kk], a1 = As[m0 + 1][kk];
    float a2 = As[m0 + 2][kk], a3 = As[m0 + 3][kk];
    float4 b = *(const float4*)&Bs[kk][n0];
    acc[0][0] += a0 * b.x; acc[0][1] += a0 * b.y; acc[0][2] += a0 * b.z; acc[0][3] += a0 * b.w;
    acc[1][0] += a1 * b.x; acc[1][1] += a1 * b.y; acc[1][2] += a1 * b.z; acc[1][3] += a1 * b.w;
    acc[2][0] += a2 * b.x; acc[2][1] += a2 * b.y; acc[2][2] += a2 * b.z; acc[2][3] += a2 * b.w;
    acc[3][0] += a3 * b.x; acc[3][1] += a3 * b.y; acc[3][2] += a3 * b.z; acc[3][3] += a3 * b.w;
  }
#pragma unroll
  for (int i = 0; i < 4; ++i) {
    int gr = row0 + m0 + i;
    if (gr < N) {
      float s = dinv[gr];
      Cb[(size_t)gr * 32 + ((col0 + n0) >> 2)] =
          fp8pk4(acc[i][0] * s, acc[i][1] * s, acc[i][2] * s, acc[i][3] * s);
    }
  }
}

// ---------------------------------------------------------------- aggregate (fp8)
// out[c,:] = fp8(relu(dinv[c]*(hh[c,:] + sum_{r} hh[r,:]) + bias))
__global__ __launch_bounds__(256) void k_aggf(const uint4* __restrict__ hh,
                                              const float* __restrict__ dinv,
                                              const int* __restrict__ rowptr,
                                              const int* __restrict__ src,
                                              const float* __restrict__ bias,
                                              uint4* __restrict__ outb, int N) {
  int tx = threadIdx.x;  // 0..7 : 16-channel chunk
  int ty = threadIdx.y;  // 0..31: node slot
  float bv[16];
#pragma unroll
  for (int i = 0; i < 16; ++i) bv[i] = bias[tx * 16 + i];

  for (int c = blockIdx.x * 32 + ty; c < N; c += gridDim.x * 32) {
    float acc[16] = {};
    fp8acc16(hh[(size_t)c * 8 + tx], acc);  // self-loop
    int j = rowptr[c], je = rowptr[c + 1];
    for (; j + 8 <= je; j += 8) {
      int r0 = src[j + 0], r1 = src[j + 1], r2 = src[j + 2], r3 = src[j + 3];
      int r4 = src[j + 4], r5 = src[j + 5], r6 = src[j + 6], r7 = src[j + 7];
      uint4 v0 = hh[(size_t)r0 * 8 + tx];
      uint4 v1 = hh[(size_t)r1 * 8 + tx];
      uint4 v2 = hh[(size_t)r2 * 8 + tx];
      uint4 v3 = hh[(size_t)r3 * 8 + tx];
      uint4 v4 = hh[(size_t)r4 * 8 + tx];
      uint4 v5 = hh[(size_t)r5 * 8 + tx];
      uint4 v6 = hh[(size_t)r6 * 8 + tx];
      uint4 v7 = hh[(size_t)r7 * 8 + tx];
      fp8acc16(v0, acc); fp8acc16(v1, acc); fp8acc16(v2, acc); fp8acc16(v3, acc);
      fp8acc16(v4, acc); fp8acc16(v5, acc); fp8acc16(v6, acc); fp8acc16(v7, acc);
    }
    for (; j < je; ++j) fp8acc16(hh[(size_t)src[j] * 8 + tx], acc);
    float s = dinv[c];
    float o[16];
#pragma unroll
    for (int i = 0; i < 16; ++i) o[i] = fmaxf(acc[i] * s + bv[i], 0.f);
    uint4 ov;
    ov.x = fp8pk4(o[0], o[1], o[2], o[3]);
    ov.y = fp8pk4(o[4], o[5], o[6], o[7]);
    ov.z = fp8pk4(o[8], o[9], o[10], o[11]);
    ov.w = fp8pk4(o[12], o[13], o[14], o[15]);
    outb[(size_t)c * 8 + tx] = ov;
  }
}

// ---------------------------------------------------------------- layer-3 collapse
__global__ __launch_bounds__(256) void k_usumf(const uint4* __restrict__ xb,
                                               const float* __restrict__ wp,
                                               const float* __restrict__ dinv,
                                               float* __restrict__ partial, int N) {
  __shared__ float red[32][129];
  int tx = threadIdx.x;  // 0..7
  int ty = threadIdx.y;  // 0..31
  float acc[16] = {};
  for (int c = blockIdx.x * 32 + ty; c < N; c += gridDim.x * 32) {
    float d = dinv[c];
    float wt = (d + wp[c]) * d;
    uint4 v = xb[(size_t)c * 8 + tx];
    fp8wacc4(v.x, wt, acc); fp8wacc4(v.y, wt, acc + 4);
    fp8wacc4(v.z, wt, acc + 8); fp8wacc4(v.w, wt, acc + 12);
  }
#pragma unroll
  for (int i = 0; i < 16; ++i) red[ty][tx * 16 + i] = acc[i];
  __syncthreads();
  for (int s = 16; s > 0; s >>= 1) {
    if (ty < s) {
#pragma unroll
      for (int i = 0; i < 16; ++i) red[ty][tx * 16 + i] += red[ty + s][tx * 16 + i];
    }
    __syncthreads();
  }
  if (ty == 0) {
#pragma unroll
    for (int i = 0; i < 16; ++i)
      partial[(size_t)blockIdx.x * CH + tx * 16 + i] = red[0][tx * 16 + i];
  }
}

// ---------------------------------------------------------------- epilogue
__global__ void k_final(const float* __restrict__ partial, int nb,
                        const float* __restrict__ W3, const float* __restrict__ b3,
                        const float* __restrict__ Wl, const float* __restrict__ bl,
                        float* __restrict__ out, float invN) {
  __shared__ float us[CH];
  __shared__ float red[CH];
  int t = threadIdx.x;
  float u = 0.f;
  for (int b = 0; b < nb; ++b) u += partial[(size_t)b * CH + t];
  us[t] = u * invN;
  __syncthreads();
  float s = 0.f;
  for (int k = 0; k < CH; ++k) s += us[k] * W3[(size_t)k * CH + t];
  float g = s + b3[t];
  red[t] = g * Wl[t];
  __syncthreads();
  for (int off = 64; off > 0; off >>= 1) {
    if (t < off) red[t] += red[t + off];
    __syncthreads();
  }
  if (t == 0) out[0] = 1.f / (1.f + expf(-(red[0] + bl[0])));
}

// ---------------------------------------------------------------- launch

extern "C" void kernel_launch(void* const* d_in, const int* in_sizes, int n_in,
                              void* d_out, int out_size, void* d_ws, size_t ws_size,
                              hipStream_t stream) {
  const float* x  = (const float*)d_in[0];
  const void*  ei = d_in[1];
  const float* W1 = (const float*)d_in[3];
  const float* b1 = (const float*)d_in[4];
  const float* W2 = (const float*)d_in[5];
  const float* b2 = (const float*)d_in[6];
  const float* W3 = (const float*)d_in[7];
  const float* b3 = (const float*)d_in[8];
  const float* Wl = (const float*)d_in[9];
  const float* bl = (const float*)d_in[10];
  float* out = (float*)d_out;

  const int N = in_sizes[0] / CH;
  const int E = in_sizes[1] / 2;
  const int NB = (N + 255) >> 8;

  char* ws = (char*)d_ws;
  size_t off = 0;
  auto alloc = [&](size_t bytes) -> void* {
    void* p = ws + off;
    off += (bytes + 511) & ~(size_t)511;
    return p;
  };
  int*   flag   = (int*)alloc(4);
  float* dinv   = (float*)alloc((size_t)N * 4);
  float* wp     = (float*)alloc((size_t)N * 4);
  int*   rowptr = (int*)alloc((size_t)(N + 1) * 4);
  int*   bcnt   = (int*)alloc(256 * 16 * 4);
  int*   bbase  = (int*)alloc(256 * 4);
  int*   gcur   = (int*)alloc(256 * 16 * 4);
  int*   rcnt   = (int*)alloc(256 * 16 * 4);
  int*   rbase  = (int*)alloc(256 * 4);
  int*   rcur   = (int*)alloc(256 * 16 * 4);
  float* part   = (float*)alloc((size_t)NBU * CH * 4);
  int*   src    = (int*)alloc((size_t)E * 4);
  int2*  pairs  = (int2*)alloc((size_t)E * 8);
  int2*  rpairs = (int2*)alloc((size_t)E * 8);
  uint4* hbuf   = (uint4*)alloc((size_t)N * CH);  // fp8 rows (128 B)
  uint4* xbuf   = (uint4*)alloc((size_t)N * CH);  // fp8 rows

  const int nCk = (E + CHUNK - 1) / CHUNK;

  // ---- preprocessing: dual bucket sort (by c for CSR, by r for wp)
  k_detect<<<1, 64, 0, stream>>>((const int*)ei, flag);
  k_init<<<32, 256, 0, stream>>>(bcnt, rcnt);
  kb_count<<<nCk, 256, 0, stream>>>(ei, flag, bcnt, rcnt, E, N);
  kb_scan<<<1, 256, 0, stream>>>(bcnt, bbase, gcur, rcnt, rbase, rcur, rowptr, NB, N);
  kb_scatter<0><<<nCk, 256, 0, stream>>>(ei, flag, gcur, pairs, E, N);
  kb_scatter<1><<<nCk, 256, 0, stream>>>(ei, flag, rcur, rpairs, E, N);
  kb_csr<<<NB, 1024, 0, stream>>>(pairs, bcnt, bbase, rowptr, src, dinv, N);
  kb_wp<<<NB, 1024, 0, stream>>>(rpairs, rcnt, rbase, dinv, wp, N);

  // ---- layers 1 & 2
  dim3 ggrid((N + 63) / 64, 2);
  dim3 ablk(8, 32);
  dim3 agrid((N + 31) / 32);

  k_gemm_f32<<<ggrid, 256, 0, stream>>>(x, W1, dinv, (unsigned*)hbuf, N);
  k_aggf<<<agrid, ablk, 0, stream>>>(hbuf, dinv, rowptr, src, b1, xbuf, N);
  k_gemm_fp8<<<ggrid, 256, 0, stream>>>(xbuf, W2, dinv, (unsigned*)hbuf, N);
  k_aggf<<<agrid, ablk, 0, stream>>>(hbuf, dinv, rowptr, src, b2, xbuf, N);

  // ---- layer 3 collapsed
  k_usumf<<<NBU, ablk, 0, stream>>>(xbuf, wp, dinv, part, N);
  k_final<<<1, CH, 0, stream>>>(part, NBU, W3, b3, Wl, bl, out, 1.0f / (float)N);
}

// Round 10
// 366.934 us; speedup vs baseline: 1.3723x; 1.1662x over previous
//
#include <hip/hip_runtime.h>

#define CH 128
#define CHUNK 4096
#define NBU 256   // k_usumf grid

typedef float v2f __attribute__((ext_vector_type(2)));

// ---------------------------------------------------------------- fp8 helpers (OCP e4m3)

__device__ __forceinline__ void fp8acc4(unsigned w, float* a) {
  v2f p0 = __builtin_amdgcn_cvt_pk_f32_fp8(w, false);
  v2f p1 = __builtin_amdgcn_cvt_pk_f32_fp8(w, true);
  a[0] += p0.x; a[1] += p0.y; a[2] += p1.x; a[3] += p1.y;
}
__device__ __forceinline__ void fp8acc16(uint4 v, float* a) {
  fp8acc4(v.x, a); fp8acc4(v.y, a + 4); fp8acc4(v.z, a + 8); fp8acc4(v.w, a + 12);
}
__device__ __forceinline__ void fp8wacc4(unsigned w, float wt, float* a) {
  v2f p0 = __builtin_amdgcn_cvt_pk_f32_fp8(w, false);
  v2f p1 = __builtin_amdgcn_cvt_pk_f32_fp8(w, true);
  a[0] += wt * p0.x; a[1] += wt * p0.y; a[2] += wt * p1.x; a[3] += wt * p1.y;
}
__device__ __forceinline__ void fp8st4(unsigned w, float* d) {
  v2f p0 = __builtin_amdgcn_cvt_pk_f32_fp8(w, false);
  v2f p1 = __builtin_amdgcn_cvt_pk_f32_fp8(w, true);
  d[0] = p0.x; d[1] = p0.y; d[2] = p1.x; d[3] = p1.y;
}
__device__ __forceinline__ unsigned fp8pk4(float a, float b, float c, float d) {
  int w = 0;
  w = __builtin_amdgcn_cvt_pk_fp8_f32(a, b, w, false);
  w = __builtin_amdgcn_cvt_pk_fp8_f32(c, d, w, true);
  return (unsigned)w;
}

// ---------------------------------------------------------------- utilities

__device__ __forceinline__ int edge_at(const void* ei, long long i, int is64) {
  if (is64) return (int)((const long long*)ei)[i];
  return ((const int*)ei)[i];
}

__global__ void k_detect(const int* ei, int* flag) {
  if (blockIdx.x == 0 && threadIdx.x == 0) {
    int is64 = 1;
    for (int k = 1; k < 128; k += 2)
      if (ei[k] != 0) { is64 = 0; break; }
    *flag = is64;
  }
}

// zero padded bcnt[256*16] and rcnt[256*16]
__global__ void k_init(int* bcnt, int* rcnt) {
  int i = blockIdx.x * 256 + threadIdx.x;
  if (i < 256 * 16) { bcnt[i] = 0; rcnt[i] = 0; }
}

// P1: per-bucket edge counts for BOTH c-buckets and r-buckets
__global__ __launch_bounds__(256) void kb_count(const void* ei, const int* flag,
                                                int* bcnt, int* rcnt, int E, int N) {
  __shared__ int hist[256], rhist[256];
  int t = threadIdx.x;
  hist[t] = 0; rhist[t] = 0;
  __syncthreads();
  int f = *flag;
  for (int e = blockIdx.x * 256 + t; e < E; e += gridDim.x * 256) {
    int r = edge_at(ei, e, f);
    int c = edge_at(ei, (long long)E + e, f);
    if ((unsigned)r < (unsigned)N && (unsigned)c < (unsigned)N) {
      atomicAdd(&hist[c >> 8], 1);
      atomicAdd(&rhist[r >> 8], 1);
    }
  }
  __syncthreads();
  if (hist[t] > 0) atomicAdd(&bcnt[t * 16], hist[t]);
  if (rhist[t] > 0) atomicAdd(&rcnt[t * 16], rhist[t]);
}

// P2: scan both bucket-count arrays -> bases + cursors; rowptr[N]=total
__global__ void kb_scan(const int* bcnt, int* bbase, int* gcursor,
                        const int* rcnt, int* rbase, int* rcursor,
                        int* rowptr, int NB, int N) {
  __shared__ int tmp[256];
  int t = threadIdx.x;
  int v = (t < NB) ? bcnt[t * 16] : 0;
  tmp[t] = v;
  __syncthreads();
  for (int off = 1; off < 256; off <<= 1) {
    int u = (t >= off) ? tmp[t - off] : 0;
    __syncthreads();
    tmp[t] += u;
    __syncthreads();
  }
  bbase[t] = tmp[t] - v;
  gcursor[t * 16] = tmp[t] - v;
  if (t == 255) rowptr[N] = tmp[255];
  __syncthreads();
  int rv = (t < NB) ? rcnt[t * 16] : 0;
  tmp[t] = rv;
  __syncthreads();
  for (int off = 1; off < 256; off <<= 1) {
    int u = (t >= off) ? tmp[t - off] : 0;
    __syncthreads();
    tmp[t] += u;
    __syncthreads();
  }
  rbase[t] = tmp[t] - rv;
  rcursor[t * 16] = tmp[t] - rv;
}

// P3: bucket-sort edges by KEY into dst[] via LDS staging.
template <int KEYSEL>
__global__ __launch_bounds__(256) void kb_scatter(const void* ei, const int* flag,
                                                  int* gcursor, int2* dst,
                                                  int E, int N) {
  __shared__ int hist[256], lbase[256], lcur[256], gbl[256], tmp[256];
  __shared__ int2 stage[CHUNK];
  int t = threadIdx.x;
  int e0 = blockIdx.x * CHUNK;
  int f = *flag;
  hist[t] = 0;
  __syncthreads();
  int rr[16], cc[16];
#pragma unroll
  for (int k = 0; k < 16; ++k) {
    int e = e0 + k * 256 + t;
    rr[k] = 0; cc[k] = -1;
    if (e < E) {
      int r = edge_at(ei, e, f);
      int c = edge_at(ei, (long long)E + e, f);
      if ((unsigned)r < (unsigned)N && (unsigned)c < (unsigned)N) {
        rr[k] = r; cc[k] = c;
        int key = KEYSEL ? r : c;
        atomicAdd(&hist[key >> 8], 1);
      }
    }
  }
  __syncthreads();
  int v = hist[t];
  tmp[t] = v;
  __syncthreads();
  for (int off = 1; off < 256; off <<= 1) {
    int u = (t >= off) ? tmp[t - off] : 0;
    __syncthreads();
    tmp[t] += u;
    __syncthreads();
  }
  lbase[t] = tmp[t] - v;
  lcur[t] = tmp[t] - v;
  if (v > 0) gbl[t] = atomicAdd(&gcursor[t * 16], v);
  __syncthreads();
#pragma unroll
  for (int k = 0; k < 16; ++k) {
    if (cc[k] >= 0) {
      int key = KEYSEL ? rr[k] : cc[k];
      int b = key >> 8;
      int pos = atomicAdd(&lcur[b], 1);
      stage[pos] = make_int2(rr[k], cc[k]);
    }
  }
  __syncthreads();
  int n = tmp[255];
  for (int i = t; i < n; i += 256) {
    int2 p = stage[i];
    int key = KEYSEL ? p.x : p.y;
    int b = key >> 8;
    dst[gbl[b] + (i - lbase[b])] = p;
  }
}

// P4: per-bucket CSR build + dinv. 1024 threads/block.
__global__ __launch_bounds__(1024) void kb_csr(const int2* __restrict__ pairs,
                                               const int* __restrict__ bcnt,
                                               const int* __restrict__ bbase,
                                               int* rowptr, int* src,
                                               float* dinv, int N) {
  __shared__ int hist[256], lcur[256], tmp[256];
  int t = threadIdx.x;
  int b = blockIdx.x;
  int node0 = b << 8;
  int nn = min(256, N - node0);
  int base = bbase[b];
  int cnt = bcnt[b * 16];
  if (t < 256) hist[t] = 0;
  __syncthreads();
  for (int j = t; j < cnt; j += 1024)
    atomicAdd(&hist[pairs[base + j].y - node0], 1);
  __syncthreads();
  if (t < 256) tmp[t] = hist[t];
  __syncthreads();
  for (int off = 1; off < 256; off <<= 1) {
    int u = (t < 256 && t >= off) ? tmp[t - off] : 0;
    __syncthreads();
    if (t < 256) tmp[t] += u;
    __syncthreads();
  }
  if (t < 256) {
    int v = hist[t];
    lcur[t] = tmp[t] - v;
    if (t < nn) {
      rowptr[node0 + t] = base + tmp[t] - v;
      dinv[node0 + t] = rsqrtf((float)(v + 1));  // +1 self-loop
    }
  }
  __syncthreads();
  for (int j = t; j < cnt; j += 1024) {
    int2 p = pairs[base + j];
    int pos = atomicAdd(&lcur[p.y - node0], 1);
    src[base + pos] = p.x;
  }
}

// P5: wp accumulation from r-sorted pairs — LDS atomics only
__global__ __launch_bounds__(1024) void kb_wp(const int2* __restrict__ rpairs,
                                              const int* __restrict__ rcnt,
                                              const int* __restrict__ rbase,
                                              const float* __restrict__ dinv,
                                              float* __restrict__ wp, int N) {
  __shared__ float wpl[256];
  int t = threadIdx.x;
  int b = blockIdx.x;
  int node0 = b << 8;
  int nn = min(256, N - node0);
  int base = rbase[b];
  int cnt = rcnt[b * 16];
  if (t < 256) wpl[t] = 0.f;
  __syncthreads();
  for (int j = t; j < cnt; j += 1024) {
    int2 p = rpairs[base + j];
    atomicAdd(&wpl[p.x - node0], dinv[p.y]);
  }
  __syncthreads();
  if (t < nn) wp[node0 + t] = wpl[t];
}

// ---------------------------------------------------------------- GEMMs
// Cb[r,:] = fp8( dinv[r] * (A[r,:] @ W) ), W fp32 128x128

__global__ __launch_bounds__(256) void k_gemm_f32(const float* __restrict__ A,
                                                  const float* __restrict__ W,
                                                  const float* __restrict__ dinv,
                                                  unsigned* __restrict__ Cb, int N) {
  __shared__ float As[64][128];
  __shared__ float Bs[128][64];
  int tid = threadIdx.x;
  int row0 = blockIdx.x * 64;
  int col0 = blockIdx.y * 64;
  {
    int k4 = tid & 31, m = tid >> 5;
    for (int mm = m; mm < 64; mm += 8) {
      int gr = row0 + mm;
      float4 v = make_float4(0.f, 0.f, 0.f, 0.f);
      if (gr < N) v = ((const float4*)A)[(size_t)gr * 32 + k4];
      *(float4*)&As[mm][k4 * 4] = v;
    }
    int n4 = tid & 15, kr = tid >> 4;
    for (int kk = kr; kk < 128; kk += 16) {
      float4 v = ((const float4*)W)[(size_t)kk * 32 + (col0 >> 2) + n4];
      *(float4*)&Bs[kk][n4 * 4] = v;
    }
  }
  __syncthreads();
  int tx = tid & 15, ty = tid >> 4;
  int m0 = ty * 4, n0 = tx * 4;
  float acc[4][4] = {};
#pragma unroll 8
  for (int k = 0; k < 128; ++k) {
    int kk = (k + ty * 33) & 127;
    float a0 = As[m0 + 0][kk], a1 = As[m0 + 1][kk];
    float a2 = As[m0 + 2][kk], a3 = As[m0 + 3][kk];
    float4 b = *(const float4*)&Bs[kk][n0];
    acc[0][0] += a0 * b.x; acc[0][1] += a0 * b.y; acc[0][2] += a0 * b.z; acc[0][3] += a0 * b.w;
    acc[1][0] += a1 * b.x; acc[1][1] += a1 * b.y; acc[1][2] += a1 * b.z; acc[1][3] += a1 * b.w;
    acc[2][0] += a2 * b.x; acc[2][1] += a2 * b.y; acc[2][2] += a2 * b.z; acc[2][3] += a2 * b.w;
    acc[3][0] += a3 * b.x; acc[3][1] += a3 * b.y; acc[3][2] += a3 * b.z; acc[3][3] += a3 * b.w;
  }
#pragma unroll
  for (int i = 0; i < 4; ++i) {
    int gr = row0 + m0 + i;
    if (gr < N) {
      float s = dinv[gr];
      Cb[(size_t)gr * 32 + ((col0 + n0) >> 2)] =
          fp8pk4(acc[i][0] * s, acc[i][1] * s, acc[i][2] * s, acc[i][3] * s);
    }
  }
}

__global__ __launch_bounds__(256) void k_gemm_fp8(const uint4* __restrict__ Ab,
                                                  const float* __restrict__ W,
                                                  const float* __restrict__ dinv,
                                                  unsigned* __restrict__ Cb, int N) {
  __shared__ float As[64][128];
  __shared__ float Bs[128][64];
  int tid = threadIdx.x;
  int row0 = blockIdx.x * 64;
  int col0 = blockIdx.y * 64;
  {
    int k4 = tid & 7, m = tid >> 3;  // 8 uint4 per 128-ch fp8 row
    for (int mm = m; mm < 64; mm += 32) {
      int gr = row0 + mm;
      uint4 v = make_uint4(0, 0, 0, 0);
      if (gr < N) v = Ab[(size_t)gr * 8 + k4];
      float* d = &As[mm][k4 * 16];
      fp8st4(v.x, d); fp8st4(v.y, d + 4); fp8st4(v.z, d + 8); fp8st4(v.w, d + 12);
    }
    int n4 = tid & 15, kr = tid >> 4;
    for (int kk = kr; kk < 128; kk += 16) {
      float4 v = ((const float4*)W)[(size_t)kk * 32 + (col0 >> 2) + n4];
      *(float4*)&Bs[kk][n4 * 4] = v;
    }
  }
  __syncthreads();
  int tx = tid & 15, ty = tid >> 4;
  int m0 = ty * 4, n0 = tx * 4;
  float acc[4][4] = {};
#pragma unroll 8
  for (int k = 0; k < 128; ++k) {
    int kk = (k + ty * 33) & 127;
    float a0 = As[m0 + 0][kk], a1 = As[m0 + 1][kk];
    float a2 = As[m0 + 2][kk], a3 = As[m0 + 3][kk];
    float4 b = *(const float4*)&Bs[kk][n0];
    acc[0][0] += a0 * b.x; acc[0][1] += a0 * b.y; acc[0][2] += a0 * b.z; acc[0][3] += a0 * b.w;
    acc[1][0] += a1 * b.x; acc[1][1] += a1 * b.y; acc[1][2] += a1 * b.z; acc[1][3] += a1 * b.w;
    acc[2][0] += a2 * b.x; acc[2][1] += a2 * b.y; acc[2][2] += a2 * b.z; acc[2][3] += a2 * b.w;
    acc[3][0] += a3 * b.x; acc[3][1] += a3 * b.y; acc[3][2] += a3 * b.z; acc[3][3] += a3 * b.w;
  }
#pragma unroll
  for (int i = 0; i < 4; ++i) {
    int gr = row0 + m0 + i;
    if (gr < N) {
      float s = dinv[gr];
      Cb[(size_t)gr * 32 + ((col0 + n0) >> 2)] =
          fp8pk4(acc[i][0] * s, acc[i][1] * s, acc[i][2] * s, acc[i][3] * s);
    }
  }
}

// ---------------------------------------------------------------- aggregate (fp8)
__global__ __launch_bounds__(256) void k_aggf(const uint4* __restrict__ hh,
                                              const float* __restrict__ dinv,
                                              const int* __restrict__ rowptr,
                                              const int* __restrict__ src,
                                              const float* __restrict__ bias,
                                              uint4* __restrict__ outb, int N) {
  int tx = threadIdx.x;  // 0..7 : 16-channel chunk
  int ty = threadIdx.y;  // 0..31: node slot
  float bv[16];
#pragma unroll
  for (int i = 0; i < 16; ++i) bv[i] = bias[tx * 16 + i];

  for (int c = blockIdx.x * 32 + ty; c < N; c += gridDim.x * 32) {
    float acc[16] = {};
    fp8acc16(hh[(size_t)c * 8 + tx], acc);  // self-loop
    int j = rowptr[c], je = rowptr[c + 1];
    for (; j + 8 <= je; j += 8) {
      int r0 = src[j + 0], r1 = src[j + 1], r2 = src[j + 2], r3 = src[j + 3];
      int r4 = src[j + 4], r5 = src[j + 5], r6 = src[j + 6], r7 = src[j + 7];
      uint4 v0 = hh[(size_t)r0 * 8 + tx];
      uint4 v1 = hh[(size_t)r1 * 8 + tx];
      uint4 v2 = hh[(size_t)r2 * 8 + tx];
      uint4 v3 = hh[(size_t)r3 * 8 + tx];
      uint4 v4 = hh[(size_t)r4 * 8 + tx];
      uint4 v5 = hh[(size_t)r5 * 8 + tx];
      uint4 v6 = hh[(size_t)r6 * 8 + tx];
      uint4 v7 = hh[(size_t)r7 * 8 + tx];
      fp8acc16(v0, acc); fp8acc16(v1, acc); fp8acc16(v2, acc); fp8acc16(v3, acc);
      fp8acc16(v4, acc); fp8acc16(v5, acc); fp8acc16(v6, acc); fp8acc16(v7, acc);
    }
    for (; j < je; ++j) fp8acc16(hh[(size_t)src[j] * 8 + tx], acc);
    float s = dinv[c];
    float o[16];
#pragma unroll
    for (int i = 0; i < 16; ++i) o[i] = fmaxf(acc[i] * s + bv[i], 0.f);
    uint4 ov;
    ov.x = fp8pk4(o[0], o[1], o[2], o[3]);
    ov.y = fp8pk4(o[4], o[5], o[6], o[7]);
    ov.z = fp8pk4(o[8], o[9], o[10], o[11]);
    ov.w = fp8pk4(o[12], o[13], o[14], o[15]);
    outb[(size_t)c * 8 + tx] = ov;
  }
}

// ---------------------------------------------------------------- layer-3 collapse
__global__ __launch_bounds__(256) void k_usumf(const uint4* __restrict__ xb,
                                               const float* __restrict__ wp,
                                               const float* __restrict__ dinv,
                                               float* __restrict__ partial, int N) {
  __shared__ float red[32][129];
  int tx = threadIdx.x;  // 0..7
  int ty = threadIdx.y;  // 0..31
  float acc[16] = {};
  for (int c = blockIdx.x * 32 + ty; c < N; c += gridDim.x * 32) {
    float d = dinv[c];
    float wt = (d + wp[c]) * d;
    uint4 v = xb[(size_t)c * 8 + tx];
    fp8wacc4(v.x, wt, acc); fp8wacc4(v.y, wt, acc + 4);
    fp8wacc4(v.z, wt, acc + 8); fp8wacc4(v.w, wt, acc + 12);
  }
#pragma unroll
  for (int i = 0; i < 16; ++i) red[ty][tx * 16 + i] = acc[i];
  __syncthreads();
  for (int s = 16; s > 0; s >>= 1) {
    if (ty < s) {
#pragma unroll
      for (int i = 0; i < 16; ++i) red[ty][tx * 16 + i] += red[ty + s][tx * 16 + i];
    }
    __syncthreads();
  }
  if (ty == 0) {
#pragma unroll
    for (int i = 0; i < 16; ++i)
      partial[(size_t)blockIdx.x * CH + tx * 16 + i] = red[0][tx * 16 + i];
  }
}

// ---------------------------------------------------------------- epilogue (1024 thr)
// R9 lesson: 1-wave serial loads = 67us. 8 waves, unrolled independent loads.
__global__ __launch_bounds__(1024) void k_final(const float* __restrict__ partial,
                                                const float* __restrict__ W3,
                                                const float* __restrict__ b3,
                                                const float* __restrict__ Wl,
                                                const float* __restrict__ bl,
                                                float* __restrict__ out, float invN) {
  __shared__ float us[CH];
  __shared__ float red[8][CH];
  int t = threadIdx.x;
  int ch = t & 127, g = t >> 7;  // g = 0..7
  // stage 1: u[ch] = sum of 256 partial rows; 32 independent loads/thread
  float s = 0.f;
#pragma unroll
  for (int b = 0; b < 32; ++b)
    s += partial[(size_t)(g * 32 + b) * CH + ch];
  red[g][ch] = s;
  __syncthreads();
  if (g == 0) {
    float u = 0.f;
#pragma unroll
    for (int k = 1; k < 8; ++k) u += red[k][ch];
    us[ch] = (s + u) * invN;
  }
  __syncthreads();
  // stage 2: S[ch] = sum_k us[k]*W3[k][ch]; 16 independent loads/thread
  float p = 0.f;
#pragma unroll
  for (int k = 0; k < 16; ++k) {
    int kk = g * 16 + k;
    p += us[kk] * W3[(size_t)kk * CH + ch];
  }
  red[g][ch] = p;
  __syncthreads();
  if (g == 0) {
    float S = red[0][ch];
#pragma unroll
    for (int k = 1; k < 8; ++k) S += red[k][ch];
    us[ch] = (S + b3[ch]) * Wl[ch];
  }
  __syncthreads();
  // stage 3: dot-reduce 128 -> 1, sigmoid
  for (int off = 64; off > 0; off >>= 1) {
    if (t < off) us[t] += us[t + off];
    __syncthreads();
  }
  if (t == 0) out[0] = 1.f / (1.f + expf(-(us[0] + bl[0])));
}

// ---------------------------------------------------------------- launch

extern "C" void kernel_launch(void* const* d_in, const int* in_sizes, int n_in,
                              void* d_out, int out_size, void* d_ws, size_t ws_size,
                              hipStream_t stream) {
  const float* x  = (const float*)d_in[0];
  const void*  ei = d_in[1];
  const float* W1 = (const float*)d_in[3];
  const float* b1 = (const float*)d_in[4];
  const float* W2 = (const float*)d_in[5];
  const float* b2 = (const float*)d_in[6];
  const float* W3 = (const float*)d_in[7];
  const float* b3 = (const float*)d_in[8];
  const float* Wl = (const float*)d_in[9];
  const float* bl = (const float*)d_in[10];
  float* out = (float*)d_out;

  const int N = in_sizes[0] / CH;
  const int E = in_sizes[1] / 2;
  const int NB = (N + 255) >> 8;

  char* ws = (char*)d_ws;
  size_t off = 0;
  auto alloc = [&](size_t bytes) -> void* {
    void* p = ws + off;
    off += (bytes + 511) & ~(size_t)511;
    return p;
  };
  int*   flag   = (int*)alloc(4);
  float* dinv   = (float*)alloc((size_t)N * 4);
  float* wp     = (float*)alloc((size_t)N * 4);
  int*   rowptr = (int*)alloc((size_t)(N + 1) * 4);
  int*   bcnt   = (int*)alloc(256 * 16 * 4);
  int*   bbase  = (int*)alloc(256 * 4);
  int*   gcur   = (int*)alloc(256 * 16 * 4);
  int*   rcnt   = (int*)alloc(256 * 16 * 4);
  int*   rbase  = (int*)alloc(256 * 4);
  int*   rcur   = (int*)alloc(256 * 16 * 4);
  float* part   = (float*)alloc((size_t)NBU * CH * 4);
  int*   src    = (int*)alloc((size_t)E * 4);
  int2*  pairs  = (int2*)alloc((size_t)E * 8);
  int2*  rpairs = (int2*)alloc((size_t)E * 8);
  uint4* hbuf   = (uint4*)alloc((size_t)N * CH);  // fp8 rows (128 B)
  uint4* xbuf   = (uint4*)alloc((size_t)N * CH);  // fp8 rows

  const int nCk = (E + CHUNK - 1) / CHUNK;

  // ---- preprocessing: dual bucket sort (by c for CSR, by r for wp)
  k_detect<<<1, 64, 0, stream>>>((const int*)ei, flag);
  k_init<<<32, 256, 0, stream>>>(bcnt, rcnt);
  kb_count<<<nCk, 256, 0, stream>>>(ei, flag, bcnt, rcnt, E, N);
  kb_scan<<<1, 256, 0, stream>>>(bcnt, bbase, gcur, rcnt, rbase, rcur, rowptr, NB, N);
  kb_scatter<0><<<nCk, 256, 0, stream>>>(ei, flag, gcur, pairs, E, N);
  kb_scatter<1><<<nCk, 256, 0, stream>>>(ei, flag, rcur, rpairs, E, N);
  kb_csr<<<NB, 1024, 0, stream>>>(pairs, bcnt, bbase, rowptr, src, dinv, N);
  kb_wp<<<NB, 1024, 0, stream>>>(rpairs, rcnt, rbase, dinv, wp, N);

  // ---- layers 1 & 2
  dim3 ggrid((N + 63) / 64, 2);
  dim3 ablk(8, 32);
  dim3 agrid((N + 31) / 32);

  k_gemm_f32<<<ggrid, 256, 0, stream>>>(x, W1, dinv, (unsigned*)hbuf, N);
  k_aggf<<<agrid, ablk, 0, stream>>>(hbuf, dinv, rowptr, src, b1, xbuf, N);
  k_gemm_fp8<<<ggrid, 256, 0, stream>>>(xbuf, W2, dinv, (unsigned*)hbuf, N);
  k_aggf<<<agrid, ablk, 0, stream>>>(hbuf, dinv, rowptr, src, b2, xbuf, N);

  // ---- layer 3 collapsed
  k_usumf<<<NBU, ablk, 0, stream>>>(xbuf, wp, dinv, part, N);
  k_final<<<1, 1024, 0, stream>>>(part, W3, b3, Wl, bl, out, 1.0f / (float)N);
}

// Round 11
// 330.411 us; speedup vs baseline: 1.5240x; 1.1105x over previous
//
#include <hip/hip_runtime.h>

#define CH 128
#define CHUNK 4096
#define NBU 256   // k_usumf grid

typedef float v2f __attribute__((ext_vector_type(2)));
typedef __attribute__((ext_vector_type(8))) short bf16x8;   // 8 bf16 (4 VGPRs)
typedef __attribute__((ext_vector_type(4))) float f32x4;    // MFMA acc

// ---------------------------------------------------------------- fp8 helpers (OCP e4m3)

__device__ __forceinline__ void fp8acc4(unsigned w, float* a) {
  v2f p0 = __builtin_amdgcn_cvt_pk_f32_fp8(w, false);
  v2f p1 = __builtin_amdgcn_cvt_pk_f32_fp8(w, true);
  a[0] += p0.x; a[1] += p0.y; a[2] += p1.x; a[3] += p1.y;
}
__device__ __forceinline__ void fp8acc16(uint4 v, float* a) {
  fp8acc4(v.x, a); fp8acc4(v.y, a + 4); fp8acc4(v.z, a + 8); fp8acc4(v.w, a + 12);
}
__device__ __forceinline__ void fp8wacc4(unsigned w, float wt, float* a) {
  v2f p0 = __builtin_amdgcn_cvt_pk_f32_fp8(w, false);
  v2f p1 = __builtin_amdgcn_cvt_pk_f32_fp8(w, true);
  a[0] += wt * p0.x; a[1] += wt * p0.y; a[2] += wt * p1.x; a[3] += wt * p1.y;
}
__device__ __forceinline__ unsigned fp8pk4(float a, float b, float c, float d) {
  int w = 0;
  w = __builtin_amdgcn_cvt_pk_fp8_f32(a, b, w, false);
  w = __builtin_amdgcn_cvt_pk_fp8_f32(c, d, w, true);
  return (unsigned)w;
}

// ---------------------------------------------------------------- bf16 helpers

__device__ __forceinline__ unsigned bfpack2(float a, float b) {
  unsigned ua = __float_as_uint(a); ua += 0x7FFF + ((ua >> 16) & 1);
  unsigned ub = __float_as_uint(b); ub += 0x7FFF + ((ub >> 16) & 1);
  return (ua >> 16) | (ub & 0xFFFF0000u);
}
__device__ __forceinline__ ushort bf16of(float a) {
  unsigned ua = __float_as_uint(a); ua += 0x7FFF + ((ua >> 16) & 1);
  return (ushort)(ua >> 16);
}
__device__ __forceinline__ uint2 fp8tobf4(unsigned w) {  // 4 fp8 -> 4 bf16
  v2f p0 = __builtin_amdgcn_cvt_pk_f32_fp8(w, false);
  v2f p1 = __builtin_amdgcn_cvt_pk_f32_fp8(w, true);
  return make_uint2(bfpack2(p0.x, p0.y), bfpack2(p1.x, p1.y));
}

// ---------------------------------------------------------------- utilities

__device__ __forceinline__ int edge_at(const void* ei, long long i, int is64) {
  if (is64) return (int)((const long long*)ei)[i];
  return ((const int*)ei)[i];
}

__global__ void k_detect(const int* ei, int* flag) {
  if (blockIdx.x == 0 && threadIdx.x == 0) {
    int is64 = 1;
    for (int k = 1; k < 128; k += 2)
      if (ei[k] != 0) { is64 = 0; break; }
    *flag = is64;
  }
}

__global__ void k_init(int* bcnt, int* rcnt) {
  int i = blockIdx.x * 256 + threadIdx.x;
  if (i < 256 * 16) { bcnt[i] = 0; rcnt[i] = 0; }
}

// one-time weight prep: Wt1[n][k]=bf16(W1[k][n]); Wt2[n][kn]=bf16(W2[orig(kn)][n]);
// permuted biases. ch_new = (c&15)*8 + (c>>4); orig(kn) = (kn&7)*16 + (kn>>3).
__global__ void k_prep(const float* __restrict__ W1, const float* __restrict__ b1,
                       const float* __restrict__ W2, const float* __restrict__ b2,
                       ushort* __restrict__ Wt1, ushort* __restrict__ Wt2,
                       float* __restrict__ b1p, float* __restrict__ b2p) {
  int t = threadIdx.x;
  for (int i = t; i < 128 * 128; i += 256) {
    int n = i >> 7, k = i & 127;
    Wt1[i] = bf16of(W1[(size_t)k * CH + n]);
    int ko = (k & 7) * 16 + (k >> 3);
    Wt2[i] = bf16of(W2[(size_t)ko * CH + n]);
  }
  if (t < CH) {
    int o = (t & 7) * 16 + (t >> 3);
    b1p[t] = b1[o];
    b2p[t] = b2[o];
  }
}

// P1: per-bucket edge counts for BOTH c-buckets and r-buckets
__global__ __launch_bounds__(256) void kb_count(const void* ei, const int* flag,
                                                int* bcnt, int* rcnt, int E, int N) {
  __shared__ int hist[256], rhist[256];
  int t = threadIdx.x;
  hist[t] = 0; rhist[t] = 0;
  __syncthreads();
  int f = *flag;
  for (int e = blockIdx.x * 256 + t; e < E; e += gridDim.x * 256) {
    int r = edge_at(ei, e, f);
    int c = edge_at(ei, (long long)E + e, f);
    if ((unsigned)r < (unsigned)N && (unsigned)c < (unsigned)N) {
      atomicAdd(&hist[c >> 8], 1);
      atomicAdd(&rhist[r >> 8], 1);
    }
  }
  __syncthreads();
  if (hist[t] > 0) atomicAdd(&bcnt[t * 16], hist[t]);
  if (rhist[t] > 0) atomicAdd(&rcnt[t * 16], rhist[t]);
}

// P2: scan both bucket-count arrays -> bases + cursors; rowptr[N]=total
__global__ void kb_scan(const int* bcnt, int* bbase, int* gcursor,
                        const int* rcnt, int* rbase, int* rcursor,
                        int* rowptr, int NB, int N) {
  __shared__ int tmp[256];
  int t = threadIdx.x;
  int v = (t < NB) ? bcnt[t * 16] : 0;
  tmp[t] = v;
  __syncthreads();
  for (int off = 1; off < 256; off <<= 1) {
    int u = (t >= off) ? tmp[t - off] : 0;
    __syncthreads();
    tmp[t] += u;
    __syncthreads();
  }
  bbase[t] = tmp[t] - v;
  gcursor[t * 16] = tmp[t] - v;
  if (t == 255) rowptr[N] = tmp[255];
  __syncthreads();
  int rv = (t < NB) ? rcnt[t * 16] : 0;
  tmp[t] = rv;
  __syncthreads();
  for (int off = 1; off < 256; off <<= 1) {
    int u = (t >= off) ? tmp[t - off] : 0;
    __syncthreads();
    tmp[t] += u;
    __syncthreads();
  }
  rbase[t] = tmp[t] - rv;
  rcursor[t * 16] = tmp[t] - rv;
}

// P3: bucket-sort edges by KEY into dst[] via LDS staging.
template <int KEYSEL>
__global__ __launch_bounds__(256) void kb_scatter(const void* ei, const int* flag,
                                                  int* gcursor, int2* dst,
                                                  int E, int N) {
  __shared__ int hist[256], lbase[256], lcur[256], gbl[256], tmp[256];
  __shared__ int2 stage[CHUNK];
  int t = threadIdx.x;
  int e0 = blockIdx.x * CHUNK;
  int f = *flag;
  hist[t] = 0;
  __syncthreads();
  int rr[16], cc[16];
#pragma unroll
  for (int k = 0; k < 16; ++k) {
    int e = e0 + k * 256 + t;
    rr[k] = 0; cc[k] = -1;
    if (e < E) {
      int r = edge_at(ei, e, f);
      int c = edge_at(ei, (long long)E + e, f);
      if ((unsigned)r < (unsigned)N && (unsigned)c < (unsigned)N) {
        rr[k] = r; cc[k] = c;
        int key = KEYSEL ? r : c;
        atomicAdd(&hist[key >> 8], 1);
      }
    }
  }
  __syncthreads();
  int v = hist[t];
  tmp[t] = v;
  __syncthreads();
  for (int off = 1; off < 256; off <<= 1) {
    int u = (t >= off) ? tmp[t - off] : 0;
    __syncthreads();
    tmp[t] += u;
    __syncthreads();
  }
  lbase[t] = tmp[t] - v;
  lcur[t] = tmp[t] - v;
  if (v > 0) gbl[t] = atomicAdd(&gcursor[t * 16], v);
  __syncthreads();
#pragma unroll
  for (int k = 0; k < 16; ++k) {
    if (cc[k] >= 0) {
      int key = KEYSEL ? rr[k] : cc[k];
      int b = key >> 8;
      int pos = atomicAdd(&lcur[b], 1);
      stage[pos] = make_int2(rr[k], cc[k]);
    }
  }
  __syncthreads();
  int n = tmp[255];
  for (int i = t; i < n; i += 256) {
    int2 p = stage[i];
    int key = KEYSEL ? p.x : p.y;
    int b = key >> 8;
    dst[gbl[b] + (i - lbase[b])] = p;
  }
}

// P4: per-bucket CSR build + dinv. 1024 threads/block.
__global__ __launch_bounds__(1024) void kb_csr(const int2* __restrict__ pairs,
                                               const int* __restrict__ bcnt,
                                               const int* __restrict__ bbase,
                                               int* rowptr, int* src,
                                               float* dinv, int N) {
  __shared__ int hist[256], lcur[256], tmp[256];
  int t = threadIdx.x;
  int b = blockIdx.x;
  int node0 = b << 8;
  int nn = min(256, N - node0);
  int base = bbase[b];
  int cnt = bcnt[b * 16];
  if (t < 256) hist[t] = 0;
  __syncthreads();
  for (int j = t; j < cnt; j += 1024)
    atomicAdd(&hist[pairs[base + j].y - node0], 1);
  __syncthreads();
  if (t < 256) tmp[t] = hist[t];
  __syncthreads();
  for (int off = 1; off < 256; off <<= 1) {
    int u = (t < 256 && t >= off) ? tmp[t - off] : 0;
    __syncthreads();
    if (t < 256) tmp[t] += u;
    __syncthreads();
  }
  if (t < 256) {
    int v = hist[t];
    lcur[t] = tmp[t] - v;
    if (t < nn) {
      rowptr[node0 + t] = base + tmp[t] - v;
      dinv[node0 + t] = rsqrtf((float)(v + 1));  // +1 self-loop
    }
  }
  __syncthreads();
  for (int j = t; j < cnt; j += 1024) {
    int2 p = pairs[base + j];
    int pos = atomicAdd(&lcur[p.y - node0], 1);
    src[base + pos] = p.x;
  }
}

// P5: wp accumulation from r-sorted pairs — LDS atomics only
__global__ __launch_bounds__(1024) void kb_wp(const int2* __restrict__ rpairs,
                                              const int* __restrict__ rcnt,
                                              const int* __restrict__ rbase,
                                              const float* __restrict__ dinv,
                                              float* __restrict__ wp, int N) {
  __shared__ float wpl[256];
  int t = threadIdx.x;
  int b = blockIdx.x;
  int node0 = b << 8;
  int nn = min(256, N - node0);
  int base = rbase[b];
  int cnt = rcnt[b * 16];
  if (t < 256) wpl[t] = 0.f;
  __syncthreads();
  for (int j = t; j < cnt; j += 1024) {
    int2 p = rpairs[base + j];
    atomicAdd(&wpl[p.x - node0], dinv[p.y]);
  }
  __syncthreads();
  if (t < nn) wp[node0 + t] = wpl[t];
}

// ---------------------------------------------------------------- MFMA GEMM
// Cb[r][ch_new] = fp8( dinv[r] * (A[r,:] @ W)[orig(ch_new)] )
// A: fp32 (FP8A=0) or fp8 (FP8A=1) rows; Wt bf16 [n][k] (k pre-permuted for FP8A=1).
// 16x16x32 bf16 MFMA. A-frag: A[m=lane&15][k=quad*8+j]; B-frag mirrored;
// C/D: col=lane&15, row=quad*4+reg. Lane's 8 cols {c0+16nt} -> contiguous in
// permuted channel order -> coalesced dwordx2 fp8 stores, no LDS repack.
template <int FP8A>
__global__ __launch_bounds__(256) void k_gemm_m(const void* __restrict__ Av,
                                                const ushort* __restrict__ Wt,
                                                const float* __restrict__ dinv,
                                                uint2* __restrict__ Cb, int N) {
  __shared__ __align__(16) ushort As[64 * 136];   // pad 136: 2-way max conflicts
  __shared__ __align__(16) ushort Bs[128 * 136];
  int t = threadIdx.x;
  int row0 = blockIdx.x * 64;

  if (FP8A == 0) {
    const float4* A = (const float4*)Av;  // [N][32]
    int k4 = t & 31, m0 = t >> 5;
    for (int mm = m0; mm < 64; mm += 8) {
      int gr = row0 + mm;
      float4 v = make_float4(0.f, 0.f, 0.f, 0.f);
      if (gr < N) v = A[(size_t)gr * 32 + k4];
      *(uint2*)&As[mm * 136 + k4 * 4] = make_uint2(bfpack2(v.x, v.y), bfpack2(v.z, v.w));
    }
  } else {
    const uint4* A = (const uint4*)Av;  // [N][8] (128 fp8)
    int k8 = t & 7, m0 = t >> 3;
    for (int mm = m0; mm < 64; mm += 32) {
      int gr = row0 + mm;
      uint4 v = make_uint4(0, 0, 0, 0);
      if (gr < N) v = A[(size_t)gr * 8 + k8];
      ushort* d = &As[mm * 136 + k8 * 16];
      *(uint2*)&d[0]  = fp8tobf4(v.x);
      *(uint2*)&d[4]  = fp8tobf4(v.y);
      *(uint2*)&d[8]  = fp8tobf4(v.z);
      *(uint2*)&d[12] = fp8tobf4(v.w);
    }
  }
  {
    const uint4* W4 = (const uint4*)Wt;  // 16 uint4 per 128-bf16 row
    int rw = t >> 1, half = t & 1;
#pragma unroll
    for (int i = 0; i < 8; ++i) {
      uint4 v = W4[rw * 16 + half * 8 + i];
      *(uint4*)&Bs[rw * 136 + half * 64 + i * 8] = v;
    }
  }
  __syncthreads();

  int lane = t & 63, w = t >> 6;
  int m = lane & 15, quad = lane >> 4;
  f32x4 acc[8] = {};
#pragma unroll
  for (int kb = 0; kb < 128; kb += 32) {
    bf16x8 af = *(const bf16x8*)&As[(w * 16 + m) * 136 + kb + quad * 8];
#pragma unroll
    for (int nt = 0; nt < 8; ++nt) {
      bf16x8 bfv = *(const bf16x8*)&Bs[(nt * 16 + m) * 136 + kb + quad * 8];
      acc[nt] = __builtin_amdgcn_mfma_f32_16x16x32_bf16(af, bfv, acc[nt], 0, 0, 0);
    }
  }
#pragma unroll
  for (int reg = 0; reg < 4; ++reg) {
    int gr = row0 + w * 16 + quad * 4 + reg;
    if (gr < N) {
      float s = dinv[gr];
      unsigned w0 = fp8pk4(acc[0][reg] * s, acc[1][reg] * s, acc[2][reg] * s, acc[3][reg] * s);
      unsigned w1 = fp8pk4(acc[4][reg] * s, acc[5][reg] * s, acc[6][reg] * s, acc[7][reg] * s);
      Cb[(size_t)gr * 16 + m] = make_uint2(w0, w1);
    }
  }
}

// ---------------------------------------------------------------- aggregate (fp8)
__global__ __launch_bounds__(256) void k_aggf(const uint4* __restrict__ hh,
                                              const float* __restrict__ dinv,
                                              const int* __restrict__ rowptr,
                                              const int* __restrict__ src,
                                              const float* __restrict__ bias,
                                              uint4* __restrict__ outb, int N) {
  int tx = threadIdx.x;  // 0..7 : 16-channel chunk
  int ty = threadIdx.y;  // 0..31: node slot
  float bv[16];
#pragma unroll
  for (int i = 0; i < 16; ++i) bv[i] = bias[tx * 16 + i];

  for (int c = blockIdx.x * 32 + ty; c < N; c += gridDim.x * 32) {
    float acc[16] = {};
    fp8acc16(hh[(size_t)c * 8 + tx], acc);  // self-loop
    int j = rowptr[c], je = rowptr[c + 1];
    for (; j + 8 <= je; j += 8) {
      int r0 = src[j + 0], r1 = src[j + 1], r2 = src[j + 2], r3 = src[j + 3];
      int r4 = src[j + 4], r5 = src[j + 5], r6 = src[j + 6], r7 = src[j + 7];
      uint4 v0 = hh[(size_t)r0 * 8 + tx];
      uint4 v1 = hh[(size_t)r1 * 8 + tx];
      uint4 v2 = hh[(size_t)r2 * 8 + tx];
      uint4 v3 = hh[(size_t)r3 * 8 + tx];
      uint4 v4 = hh[(size_t)r4 * 8 + tx];
      uint4 v5 = hh[(size_t)r5 * 8 + tx];
      uint4 v6 = hh[(size_t)r6 * 8 + tx];
      uint4 v7 = hh[(size_t)r7 * 8 + tx];
      fp8acc16(v0, acc); fp8acc16(v1, acc); fp8acc16(v2, acc); fp8acc16(v3, acc);
      fp8acc16(v4, acc); fp8acc16(v5, acc); fp8acc16(v6, acc); fp8acc16(v7, acc);
    }
    for (; j < je; ++j) fp8acc16(hh[(size_t)src[j] * 8 + tx], acc);
    float s = dinv[c];
    float o[16];
#pragma unroll
    for (int i = 0; i < 16; ++i) o[i] = fmaxf(acc[i] * s + bv[i], 0.f);
    uint4 ov;
    ov.x = fp8pk4(o[0], o[1], o[2], o[3]);
    ov.y = fp8pk4(o[4], o[5], o[6], o[7]);
    ov.z = fp8pk4(o[8], o[9], o[10], o[11]);
    ov.w = fp8pk4(o[12], o[13], o[14], o[15]);
    outb[(size_t)c * 8 + tx] = ov;
  }
}

// ---------------------------------------------------------------- layer-3 collapse
__global__ __launch_bounds__(256) void k_usumf(const uint4* __restrict__ xb,
                                               const float* __restrict__ wp,
                                               const float* __restrict__ dinv,
                                               float* __restrict__ partial, int N) {
  __shared__ float red[32][129];
  int tx = threadIdx.x;  // 0..7
  int ty = threadIdx.y;  // 0..31
  float acc[16] = {};
  for (int c = blockIdx.x * 32 + ty; c < N; c += gridDim.x * 32) {
    float d = dinv[c];
    float wt = (d + wp[c]) * d;
    uint4 v = xb[(size_t)c * 8 + tx];
    fp8wacc4(v.x, wt, acc); fp8wacc4(v.y, wt, acc + 4);
    fp8wacc4(v.z, wt, acc + 8); fp8wacc4(v.w, wt, acc + 12);
  }
#pragma unroll
  for (int i = 0; i < 16; ++i) red[ty][tx * 16 + i] = acc[i];
  __syncthreads();
  for (int s = 16; s > 0; s >>= 1) {
    if (ty < s) {
#pragma unroll
      for (int i = 0; i < 16; ++i) red[ty][tx * 16 + i] += red[ty + s][tx * 16 + i];
    }
    __syncthreads();
  }
  if (ty == 0) {
#pragma unroll
    for (int i = 0; i < 16; ++i)
      partial[(size_t)blockIdx.x * CH + tx * 16 + i] = red[0][tx * 16 + i];
  }
}

// ---------------------------------------------------------------- epilogue (1024 thr)
// partial/us are in PERMUTED channel order; W3 row index un-permutes.
__global__ __launch_bounds__(1024) void k_final(const float* __restrict__ partial,
                                                const float* __restrict__ W3,
                                                const float* __restrict__ b3,
                                                const float* __restrict__ Wl,
                                                const float* __restrict__ bl,
                                                float* __restrict__ out, float invN) {
  __shared__ float us[CH];
  __shared__ float red[8][CH];
  int t = threadIdx.x;
  int ch = t & 127, g = t >> 7;  // g = 0..7
  float s = 0.f;
#pragma unroll
  for (int b = 0; b < 32; ++b)
    s += partial[(size_t)(g * 32 + b) * CH + ch];
  red[g][ch] = s;
  __syncthreads();
  if (g == 0) {
    float u = 0.f;
#pragma unroll
    for (int k = 1; k < 8; ++k) u += red[k][ch];
    us[ch] = (s + u) * invN;
  }
  __syncthreads();
  float p = 0.f;
#pragma unroll
  for (int k = 0; k < 16; ++k) {
    int kk = g * 16 + k;
    int ko = (kk & 7) * 16 + (kk >> 3);  // un-permute channel
    p += us[kk] * W3[(size_t)ko * CH + ch];
  }
  red[g][ch] = p;
  __syncthreads();
  if (g == 0) {
    float S = red[0][ch];
#pragma unroll
    for (int k = 1; k < 8; ++k) S += red[k][ch];
    us[ch] = (S + b3[ch]) * Wl[ch];
  }
  __syncthreads();
  for (int off = 64; off > 0; off >>= 1) {
    if (t < off) us[t] += us[t + off];
    __syncthreads();
  }
  if (t == 0) out[0] = 1.f / (1.f + expf(-(us[0] + bl[0])));
}

// ---------------------------------------------------------------- launch

extern "C" void kernel_launch(void* const* d_in, const int* in_sizes, int n_in,
                              void* d_out, int out_size, void* d_ws, size_t ws_size,
                              hipStream_t stream) {
  const float* x  = (const float*)d_in[0];
  const void*  ei = d_in[1];
  const float* W1 = (const float*)d_in[3];
  const float* b1 = (const float*)d_in[4];
  const float* W2 = (const float*)d_in[5];
  const float* b2 = (const float*)d_in[6];
  const float* W3 = (const float*)d_in[7];
  const float* b3 = (const float*)d_in[8];
  const float* Wl = (const float*)d_in[9];
  const float* bl = (const float*)d_in[10];
  float* out = (float*)d_out;

  const int N = in_sizes[0] / CH;
  const int E = in_sizes[1] / 2;
  const int NB = (N + 255) >> 8;

  char* ws = (char*)d_ws;
  size_t off = 0;
  auto alloc = [&](size_t bytes) -> void* {
    void* p = ws + off;
    off += (bytes + 511) & ~(size_t)511;
    return p;
  };
  int*    flag   = (int*)alloc(4);
  float*  dinv   = (float*)alloc((size_t)N * 4);
  float*  wp     = (float*)alloc((size_t)N * 4);
  int*    rowptr = (int*)alloc((size_t)(N + 1) * 4);
  int*    bcnt   = (int*)alloc(256 * 16 * 4);
  int*    bbase  = (int*)alloc(256 * 4);
  int*    gcur   = (int*)alloc(256 * 16 * 4);
  int*    rcnt   = (int*)alloc(256 * 16 * 4);
  int*    rbase  = (int*)alloc(256 * 4);
  int*    rcur   = (int*)alloc(256 * 16 * 4);
  float*  part   = (float*)alloc((size_t)NBU * CH * 4);
  ushort* Wt1    = (ushort*)alloc(128 * 128 * 2);
  ushort* Wt2    = (ushort*)alloc(128 * 128 * 2);
  float*  b1p    = (float*)alloc(CH * 4);
  float*  b2p    = (float*)alloc(CH * 4);
  int*    src    = (int*)alloc((size_t)E * 4);
  int2*   pairs  = (int2*)alloc((size_t)E * 8);
  int2*   rpairs = (int2*)alloc((size_t)E * 8);
  uint4*  hbuf   = (uint4*)alloc((size_t)N * CH);  // fp8 rows (128 B)
  uint4*  xbuf   = (uint4*)alloc((size_t)N * CH);  // fp8 rows

  const int nCk = (E + CHUNK - 1) / CHUNK;

  // ---- preprocessing: dual bucket sort + weight prep
  k_detect<<<1, 64, 0, stream>>>((const int*)ei, flag);
  k_prep<<<1, 256, 0, stream>>>(W1, b1, W2, b2, Wt1, Wt2, b1p, b2p);
  k_init<<<32, 256, 0, stream>>>(bcnt, rcnt);
  kb_count<<<nCk, 256, 0, stream>>>(ei, flag, bcnt, rcnt, E, N);
  kb_scan<<<1, 256, 0, stream>>>(bcnt, bbase, gcur, rcnt, rbase, rcur, rowptr, NB, N);
  kb_scatter<0><<<nCk, 256, 0, stream>>>(ei, flag, gcur, pairs, E, N);
  kb_scatter<1><<<nCk, 256, 0, stream>>>(ei, flag, rcur, rpairs, E, N);
  kb_csr<<<NB, 1024, 0, stream>>>(pairs, bcnt, bbase, rowptr, src, dinv, N);
  kb_wp<<<NB, 1024, 0, stream>>>(rpairs, rcnt, rbase, dinv, wp, N);

  // ---- layers 1 & 2 (MFMA GEMMs + gather-aggregates)
  const int gblocks = (N + 63) / 64;
  dim3 ablk(8, 32);
  dim3 agrid((N + 31) / 32);

  k_gemm_m<0><<<gblocks, 256, 0, stream>>>(x, Wt1, dinv, (uint2*)hbuf, N);
  k_aggf<<<agrid, ablk, 0, stream>>>(hbuf, dinv, rowptr, src, b1p, xbuf, N);
  k_gemm_m<1><<<gblocks, 256, 0, stream>>>(xbuf, Wt2, dinv, (uint2*)hbuf, N);
  k_aggf<<<agrid, ablk, 0, stream>>>(hbuf, dinv, rowptr, src, b2p, xbuf, N);

  // ---- layer 3 collapsed
  k_usumf<<<NBU, ablk, 0, stream>>>(xbuf, wp, dinv, part, N);
  k_final<<<1, 1024, 0, stream>>>(part, W3, b3, Wl, bl, out, 1.0f / (float)N);
}

// Round 12
// 318.125 us; speedup vs baseline: 1.5828x; 1.0386x over previous
//
#include <hip/hip_runtime.h>

#define CH 128
#define CHUNK 4096
#define NBU 256   // k_usumf grid

typedef float v2f __attribute__((ext_vector_type(2)));
typedef __attribute__((ext_vector_type(8))) short bf16x8;   // 8 bf16 (4 VGPRs)
typedef __attribute__((ext_vector_type(4))) float f32x4;    // MFMA acc

// ---------------------------------------------------------------- fp8 helpers (OCP e4m3)

__device__ __forceinline__ void fp8acc4(unsigned w, float* a) {
  v2f p0 = __builtin_amdgcn_cvt_pk_f32_fp8(w, false);
  v2f p1 = __builtin_amdgcn_cvt_pk_f32_fp8(w, true);
  a[0] += p0.x; a[1] += p0.y; a[2] += p1.x; a[3] += p1.y;
}
__device__ __forceinline__ void fp8acc16(uint4 v, float* a) {
  fp8acc4(v.x, a); fp8acc4(v.y, a + 4); fp8acc4(v.z, a + 8); fp8acc4(v.w, a + 12);
}
__device__ __forceinline__ void fp8wacc4(unsigned w, float wt, float* a) {
  v2f p0 = __builtin_amdgcn_cvt_pk_f32_fp8(w, false);
  v2f p1 = __builtin_amdgcn_cvt_pk_f32_fp8(w, true);
  a[0] += wt * p0.x; a[1] += wt * p0.y; a[2] += wt * p1.x; a[3] += wt * p1.y;
}
__device__ __forceinline__ unsigned fp8pk4(float a, float b, float c, float d) {
  int w = 0;
  w = __builtin_amdgcn_cvt_pk_fp8_f32(a, b, w, false);
  w = __builtin_amdgcn_cvt_pk_fp8_f32(c, d, w, true);
  return (unsigned)w;
}

// ---------------------------------------------------------------- bf16 helpers

__device__ __forceinline__ unsigned bfpack2(float a, float b) {
  unsigned ua = __float_as_uint(a); ua += 0x7FFF + ((ua >> 16) & 1);
  unsigned ub = __float_as_uint(b); ub += 0x7FFF + ((ub >> 16) & 1);
  return (ua >> 16) | (ub & 0xFFFF0000u);
}
__device__ __forceinline__ ushort bf16of(float a) {
  unsigned ua = __float_as_uint(a); ua += 0x7FFF + ((ua >> 16) & 1);
  return (ushort)(ua >> 16);
}
__device__ __forceinline__ uint2 fp8tobf4(unsigned w) {  // 4 fp8 -> 4 bf16
  v2f p0 = __builtin_amdgcn_cvt_pk_f32_fp8(w, false);
  v2f p1 = __builtin_amdgcn_cvt_pk_f32_fp8(w, true);
  return make_uint2(bfpack2(p0.x, p0.y), bfpack2(p1.x, p1.y));
}

// ---------------------------------------------------------------- utilities

__device__ __forceinline__ int edge_at(const void* ei, long long i, int is64) {
  if (is64) return (int)((const long long*)ei)[i];
  return ((const int*)ei)[i];
}

// merged setup: dtype detect + counter zero + bf16 weight prep (1 block)
__global__ void k_setup(const int* ei, int* flag, int* bcnt, int* rcnt,
                        const float* __restrict__ W1, const float* __restrict__ b1,
                        const float* __restrict__ W2, const float* __restrict__ b2,
                        ushort* __restrict__ Wt1, ushort* __restrict__ Wt2,
                        float* __restrict__ b1p, float* __restrict__ b2p) {
  int t = threadIdx.x;
  if (t == 0) {
    int is64 = 1;
    for (int k = 1; k < 128; k += 2)
      if (ei[k] != 0) { is64 = 0; break; }
    *flag = is64;
  }
  for (int i = t; i < 256 * 16; i += 256) { bcnt[i] = 0; rcnt[i] = 0; }
  for (int i = t; i < 128 * 128; i += 256) {
    int n = i >> 7, k = i & 127;
    Wt1[i] = bf16of(W1[(size_t)k * CH + n]);
    int ko = (k & 7) * 16 + (k >> 3);
    Wt2[i] = bf16of(W2[(size_t)ko * CH + n]);
  }
  if (t < CH) {
    int o = (t & 7) * 16 + (t >> 3);
    b1p[t] = b1[o];
    b2p[t] = b2[o];
  }
}

// P1: per-bucket edge counts for BOTH c-buckets and r-buckets
__global__ __launch_bounds__(256) void kb_count(const void* ei, const int* flag,
                                                int* bcnt, int* rcnt, int E, int N) {
  __shared__ int hist[256], rhist[256];
  int t = threadIdx.x;
  hist[t] = 0; rhist[t] = 0;
  __syncthreads();
  int f = *flag;
  for (int e = blockIdx.x * 256 + t; e < E; e += gridDim.x * 256) {
    int r = edge_at(ei, e, f);
    int c = edge_at(ei, (long long)E + e, f);
    if ((unsigned)r < (unsigned)N && (unsigned)c < (unsigned)N) {
      atomicAdd(&hist[c >> 8], 1);
      atomicAdd(&rhist[r >> 8], 1);
    }
  }
  __syncthreads();
  if (hist[t] > 0) atomicAdd(&bcnt[t * 16], hist[t]);
  if (rhist[t] > 0) atomicAdd(&rcnt[t * 16], rhist[t]);
}

// P2: scan both bucket-count arrays -> bases + cursors; rowptr[N]=total
__global__ void kb_scan(const int* bcnt, int* bbase, int* gcursor,
                        const int* rcnt, int* rbase, int* rcursor,
                        int* rowptr, int NB, int N) {
  __shared__ int tmp[256];
  int t = threadIdx.x;
  int v = (t < NB) ? bcnt[t * 16] : 0;
  tmp[t] = v;
  __syncthreads();
  for (int off = 1; off < 256; off <<= 1) {
    int u = (t >= off) ? tmp[t - off] : 0;
    __syncthreads();
    tmp[t] += u;
    __syncthreads();
  }
  bbase[t] = tmp[t] - v;
  gcursor[t * 16] = tmp[t] - v;
  if (t == 255) rowptr[N] = tmp[255];
  __syncthreads();
  int rv = (t < NB) ? rcnt[t * 16] : 0;
  tmp[t] = rv;
  __syncthreads();
  for (int off = 1; off < 256; off <<= 1) {
    int u = (t >= off) ? tmp[t - off] : 0;
    __syncthreads();
    tmp[t] += u;
    __syncthreads();
  }
  rbase[t] = tmp[t] - rv;
  rcursor[t * 16] = tmp[t] - rv;
}

// P3: merged dual bucket-sort. One edge read; two sequential LDS-staged sorts.
// Packed 4B records: c-sort word = r | ((c&255)<<24); r-sort word = c | ((r&255)<<24).
__global__ __launch_bounds__(256) void kb_scatter2(const void* ei, const int* flag,
                                                   int* gcur, int* rcur,
                                                   unsigned* __restrict__ cpk,
                                                   unsigned* __restrict__ rpk,
                                                   int E, int N) {
  __shared__ int hist[256], lbase[256], lcur[256], gbl[256], tmp[256];
  __shared__ int2 stage[CHUNK];
  int t = threadIdx.x;
  int e0 = blockIdx.x * CHUNK;
  int f = *flag;
  int rr[16], cc[16];
#pragma unroll
  for (int k = 0; k < 16; ++k) {
    int e = e0 + k * 256 + t;
    rr[k] = 0; cc[k] = -1;
    if (e < E) {
      int r = edge_at(ei, e, f);
      int c = edge_at(ei, (long long)E + e, f);
      if ((unsigned)r < (unsigned)N && (unsigned)c < (unsigned)N) { rr[k] = r; cc[k] = c; }
    }
  }
  // ---- pass 1: key = c
  hist[t] = 0;
  __syncthreads();
#pragma unroll
  for (int k = 0; k < 16; ++k)
    if (cc[k] >= 0) atomicAdd(&hist[cc[k] >> 8], 1);
  __syncthreads();
  int v = hist[t];
  tmp[t] = v;
  __syncthreads();
  for (int off = 1; off < 256; off <<= 1) {
    int u = (t >= off) ? tmp[t - off] : 0;
    __syncthreads();
    tmp[t] += u;
    __syncthreads();
  }
  lbase[t] = tmp[t] - v;
  lcur[t] = tmp[t] - v;
  if (v > 0) gbl[t] = atomicAdd(&gcur[t * 16], v);
  __syncthreads();
#pragma unroll
  for (int k = 0; k < 16; ++k) {
    if (cc[k] >= 0) {
      int b = cc[k] >> 8;
      int pos = atomicAdd(&lcur[b], 1);
      stage[pos] = make_int2(rr[k], cc[k]);
    }
  }
  __syncthreads();
  int n = tmp[255];
  for (int i = t; i < n; i += 256) {
    int2 p = stage[i];
    int b = p.y >> 8;
    cpk[gbl[b] + (i - lbase[b])] = (unsigned)p.x | ((unsigned)(p.y & 255) << 24);
  }
  __syncthreads();
  // ---- pass 2: key = r
  hist[t] = 0;
  __syncthreads();
#pragma unroll
  for (int k = 0; k < 16; ++k)
    if (cc[k] >= 0) atomicAdd(&hist[rr[k] >> 8], 1);
  __syncthreads();
  v = hist[t];
  tmp[t] = v;
  __syncthreads();
  for (int off = 1; off < 256; off <<= 1) {
    int u = (t >= off) ? tmp[t - off] : 0;
    __syncthreads();
    tmp[t] += u;
    __syncthreads();
  }
  lbase[t] = tmp[t] - v;
  lcur[t] = tmp[t] - v;
  if (v > 0) gbl[t] = atomicAdd(&rcur[t * 16], v);
  __syncthreads();
#pragma unroll
  for (int k = 0; k < 16; ++k) {
    if (cc[k] >= 0) {
      int b = rr[k] >> 8;
      int pos = atomicAdd(&lcur[b], 1);
      stage[pos] = make_int2(cc[k], rr[k]);
    }
  }
  __syncthreads();
  n = tmp[255];
  for (int i = t; i < n; i += 256) {
    int2 p = stage[i];
    int b = p.y >> 8;
    rpk[gbl[b] + (i - lbase[b])] = (unsigned)p.x | ((unsigned)(p.y & 255) << 24);
  }
}

// P4: per-bucket CSR build + dinv from packed c-sorted records.
__global__ __launch_bounds__(1024) void kb_csr(const unsigned* __restrict__ cpk,
                                               const int* __restrict__ bcnt,
                                               const int* __restrict__ bbase,
                                               int* rowptr, int* src,
                                               float* dinv, int N) {
  __shared__ int hist[256], lcur[256], tmp[256];
  int t = threadIdx.x;
  int b = blockIdx.x;
  int node0 = b << 8;
  int nn = min(256, N - node0);
  int base = bbase[b];
  int cnt = bcnt[b * 16];
  if (t < 256) hist[t] = 0;
  __syncthreads();
  for (int j = t; j < cnt; j += 1024)
    atomicAdd(&hist[cpk[base + j] >> 24], 1);
  __syncthreads();
  if (t < 256) tmp[t] = hist[t];
  __syncthreads();
  for (int off = 1; off < 256; off <<= 1) {
    int u = (t < 256 && t >= off) ? tmp[t - off] : 0;
    __syncthreads();
    if (t < 256) tmp[t] += u;
    __syncthreads();
  }
  if (t < 256) {
    int v = hist[t];
    lcur[t] = tmp[t] - v;
    if (t < nn) {
      rowptr[node0 + t] = base + tmp[t] - v;
      dinv[node0 + t] = rsqrtf((float)(v + 1));  // +1 self-loop
    }
  }
  __syncthreads();
  for (int j = t; j < cnt; j += 1024) {
    unsigned w = cpk[base + j];
    int pos = atomicAdd(&lcur[w >> 24], 1);
    src[base + pos] = (int)(w & 0xFFFFFF);
  }
}

// P5: wp from packed r-sorted records — LDS atomics only
__global__ __launch_bounds__(1024) void kb_wp(const unsigned* __restrict__ rpk,
                                              const int* __restrict__ rcnt,
                                              const int* __restrict__ rbase,
                                              const float* __restrict__ dinv,
                                              float* __restrict__ wp, int N) {
  __shared__ float wpl[256];
  int t = threadIdx.x;
  int b = blockIdx.x;
  int node0 = b << 8;
  int nn = min(256, N - node0);
  int base = rbase[b];
  int cnt = rcnt[b * 16];
  if (t < 256) wpl[t] = 0.f;
  __syncthreads();
  for (int j = t; j < cnt; j += 1024) {
    unsigned w = rpk[base + j];
    atomicAdd(&wpl[w >> 24], dinv[w & 0xFFFFFF]);
  }
  __syncthreads();
  if (t < nn) wp[node0 + t] = wpl[t];
}

// ---------------------------------------------------------------- MFMA GEMM
// Output split into two 64B fp8 planes (ch_new 0..63 / 64..127) for L2-resident aggs.
template <int FP8A>
__global__ __launch_bounds__(256) void k_gemm_m(const void* __restrict__ Alo,
                                                const void* __restrict__ Ahi,
                                                const ushort* __restrict__ Wt,
                                                const float* __restrict__ dinv,
                                                uint2* __restrict__ Clo,
                                                uint2* __restrict__ Chi, int N) {
  __shared__ __align__(16) ushort As[64 * 136];
  __shared__ __align__(16) ushort Bs[128 * 136];
  int t = threadIdx.x;
  int row0 = blockIdx.x * 64;

  if (FP8A == 0) {
    const float4* A = (const float4*)Alo;  // [N][32]
    int k4 = t & 31, m0 = t >> 5;
    for (int mm = m0; mm < 64; mm += 8) {
      int gr = row0 + mm;
      float4 v = make_float4(0.f, 0.f, 0.f, 0.f);
      if (gr < N) v = A[(size_t)gr * 32 + k4];
      *(uint2*)&As[mm * 136 + k4 * 4] = make_uint2(bfpack2(v.x, v.y), bfpack2(v.z, v.w));
    }
  } else {
    const uint4* A0 = (const uint4*)Alo;  // [N][4] lo plane
    const uint4* A1 = (const uint4*)Ahi;  // [N][4] hi plane
    int k8 = t & 7, m0 = t >> 3;
    for (int mm = m0; mm < 64; mm += 32) {
      int gr = row0 + mm;
      uint4 v = make_uint4(0, 0, 0, 0);
      if (gr < N) v = (k8 < 4) ? A0[(size_t)gr * 4 + k8] : A1[(size_t)gr * 4 + k8 - 4];
      ushort* d = &As[mm * 136 + k8 * 16];
      *(uint2*)&d[0]  = fp8tobf4(v.x);
      *(uint2*)&d[4]  = fp8tobf4(v.y);
      *(uint2*)&d[8]  = fp8tobf4(v.z);
      *(uint2*)&d[12] = fp8tobf4(v.w);
    }
  }
  {
    const uint4* W4 = (const uint4*)Wt;
    int rw = t >> 1, half = t & 1;
#pragma unroll
    for (int i = 0; i < 8; ++i) {
      uint4 v = W4[rw * 16 + half * 8 + i];
      *(uint4*)&Bs[rw * 136 + half * 64 + i * 8] = v;
    }
  }
  __syncthreads();

  int lane = t & 63, w = t >> 6;
  int m = lane & 15, quad = lane >> 4;
  f32x4 acc[8] = {};
#pragma unroll
  for (int kb = 0; kb < 128; kb += 32) {
    bf16x8 af = *(const bf16x8*)&As[(w * 16 + m) * 136 + kb + quad * 8];
#pragma unroll
    for (int nt = 0; nt < 8; ++nt) {
      bf16x8 bfv = *(const bf16x8*)&Bs[(nt * 16 + m) * 136 + kb + quad * 8];
      acc[nt] = __builtin_amdgcn_mfma_f32_16x16x32_bf16(af, bfv, acc[nt], 0, 0, 0);
    }
  }
  uint2* pl = (m < 8) ? Clo : Chi;
#pragma unroll
  for (int reg = 0; reg < 4; ++reg) {
    int gr = row0 + w * 16 + quad * 4 + reg;
    if (gr < N) {
      float s = dinv[gr];
      unsigned w0 = fp8pk4(acc[0][reg] * s, acc[1][reg] * s, acc[2][reg] * s, acc[3][reg] * s);
      unsigned w1 = fp8pk4(acc[4][reg] * s, acc[5][reg] * s, acc[6][reg] * s, acc[7][reg] * s);
      pl[(size_t)gr * 8 + (m & 7)] = make_uint2(w0, w1);
    }
  }
}

// ---------------------------------------------------------------- aggregate (fp8, one 64B plane)
// Working set per pass = N*64B = 3.2MB -> L2-resident per XCD (R11 theory).
__global__ __launch_bounds__(256) void k_aggp(const uint4* __restrict__ hh,  // [N][4]
                                              const float* __restrict__ dinv,
                                              const int* __restrict__ rowptr,
                                              const int* __restrict__ src,
                                              const float* __restrict__ biasH,
                                              uint4* __restrict__ outp, int N) {
  int tx = threadIdx.x;  // 0..3 : 16-channel chunk
  int ty = threadIdx.y;  // 0..63: node slot
  float bv[16];
#pragma unroll
  for (int i = 0; i < 16; ++i) bv[i] = biasH[tx * 16 + i];

  for (int c = blockIdx.x * 64 + ty; c < N; c += gridDim.x * 64) {
    float acc[16] = {};
    fp8acc16(hh[(size_t)c * 4 + tx], acc);  // self-loop
    int j = rowptr[c], je = rowptr[c + 1];
    for (; j + 8 <= je; j += 8) {
      int r0 = src[j + 0], r1 = src[j + 1], r2 = src[j + 2], r3 = src[j + 3];
      int r4 = src[j + 4], r5 = src[j + 5], r6 = src[j + 6], r7 = src[j + 7];
      uint4 v0 = hh[(size_t)r0 * 4 + tx];
      uint4 v1 = hh[(size_t)r1 * 4 + tx];
      uint4 v2 = hh[(size_t)r2 * 4 + tx];
      uint4 v3 = hh[(size_t)r3 * 4 + tx];
      uint4 v4 = hh[(size_t)r4 * 4 + tx];
      uint4 v5 = hh[(size_t)r5 * 4 + tx];
      uint4 v6 = hh[(size_t)r6 * 4 + tx];
      uint4 v7 = hh[(size_t)r7 * 4 + tx];
      fp8acc16(v0, acc); fp8acc16(v1, acc); fp8acc16(v2, acc); fp8acc16(v3, acc);
      fp8acc16(v4, acc); fp8acc16(v5, acc); fp8acc16(v6, acc); fp8acc16(v7, acc);
    }
    for (; j < je; ++j) fp8acc16(hh[(size_t)src[j] * 4 + tx], acc);
    float s = dinv[c];
    float o[16];
#pragma unroll
    for (int i = 0; i < 16; ++i) o[i] = fmaxf(acc[i] * s + bv[i], 0.f);
    uint4 ov;
    ov.x = fp8pk4(o[0], o[1], o[2], o[3]);
    ov.y = fp8pk4(o[4], o[5], o[6], o[7]);
    ov.z = fp8pk4(o[8], o[9], o[10], o[11]);
    ov.w = fp8pk4(o[12], o[13], o[14], o[15]);
    outp[(size_t)c * 4 + tx] = ov;
  }
}

// ---------------------------------------------------------------- layer-3 collapse
__global__ __launch_bounds__(256) void k_usumf(const uint4* __restrict__ xlo,
                                               const uint4* __restrict__ xhi,
                                               const float* __restrict__ wp,
                                               const float* __restrict__ dinv,
                                               float* __restrict__ partial, int N) {
  __shared__ float red[32][129];
  int tx = threadIdx.x;  // 0..7
  int ty = threadIdx.y;  // 0..31
  float acc[16] = {};
  for (int c = blockIdx.x * 32 + ty; c < N; c += gridDim.x * 32) {
    float d = dinv[c];
    float wt = (d + wp[c]) * d;
    uint4 v = (tx < 4) ? xlo[(size_t)c * 4 + tx] : xhi[(size_t)c * 4 + tx - 4];
    fp8wacc4(v.x, wt, acc); fp8wacc4(v.y, wt, acc + 4);
    fp8wacc4(v.z, wt, acc + 8); fp8wacc4(v.w, wt, acc + 12);
  }
#pragma unroll
  for (int i = 0; i < 16; ++i) red[ty][tx * 16 + i] = acc[i];
  __syncthreads();
  for (int s = 16; s > 0; s >>= 1) {
    if (ty < s) {
#pragma unroll
      for (int i = 0; i < 16; ++i) red[ty][tx * 16 + i] += red[ty + s][tx * 16 + i];
    }
    __syncthreads();
  }
  if (ty == 0) {
#pragma unroll
    for (int i = 0; i < 16; ++i)
      partial[(size_t)blockIdx.x * CH + tx * 16 + i] = red[0][tx * 16 + i];
  }
}

// ---------------------------------------------------------------- epilogue (1024 thr)
__global__ __launch_bounds__(1024) void k_final(const float* __restrict__ partial,
                                                const float* __restrict__ W3,
                                                const float* __restrict__ b3,
                                                const float* __restrict__ Wl,
                                                const float* __restrict__ bl,
                                                float* __restrict__ out, float invN) {
  __shared__ float us[CH];
  __shared__ float red[8][CH];
  int t = threadIdx.x;
  int ch = t & 127, g = t >> 7;
  float s = 0.f;
#pragma unroll
  for (int b = 0; b < 32; ++b)
    s += partial[(size_t)(g * 32 + b) * CH + ch];
  red[g][ch] = s;
  __syncthreads();
  if (g == 0) {
    float u = 0.f;
#pragma unroll
    for (int k = 1; k < 8; ++k) u += red[k][ch];
    us[ch] = (s + u) * invN;
  }
  __syncthreads();
  float p = 0.f;
#pragma unroll
  for (int k = 0; k < 16; ++k) {
    int kk = g * 16 + k;
    int ko = (kk & 7) * 16 + (kk >> 3);  // un-permute channel
    p += us[kk] * W3[(size_t)ko * CH + ch];
  }
  red[g][ch] = p;
  __syncthreads();
  if (g == 0) {
    float S = red[0][ch];
#pragma unroll
    for (int k = 1; k < 8; ++k) S += red[k][ch];
    us[ch] = (S + b3[ch]) * Wl[ch];
  }
  __syncthreads();
  for (int off = 64; off > 0; off >>= 1) {
    if (t < off) us[t] += us[t + off];
    __syncthreads();
  }
  if (t == 0) out[0] = 1.f / (1.f + expf(-(us[0] + bl[0])));
}

// ---------------------------------------------------------------- launch

extern "C" void kernel_launch(void* const* d_in, const int* in_sizes, int n_in,
                              void* d_out, int out_size, void* d_ws, size_t ws_size,
                              hipStream_t stream) {
  const float* x  = (const float*)d_in[0];
  const void*  ei = d_in[1];
  const float* W1 = (const float*)d_in[3];
  const float* b1 = (const float*)d_in[4];
  const float* W2 = (const float*)d_in[5];
  const float* b2 = (const float*)d_in[6];
  const float* W3 = (const float*)d_in[7];
  const float* b3 = (const float*)d_in[8];
  const float* Wl = (const float*)d_in[9];
  const float* bl = (const float*)d_in[10];
  float* out = (float*)d_out;

  const int N = in_sizes[0] / CH;
  const int E = in_sizes[1] / 2;
  const int NB = (N + 255) >> 8;

  char* ws = (char*)d_ws;
  size_t off = 0;
  auto alloc = [&](size_t bytes) -> void* {
    void* p = ws + off;
    off += (bytes + 511) & ~(size_t)511;
    return p;
  };
  int*      flag   = (int*)alloc(4);
  float*    dinv   = (float*)alloc((size_t)N * 4);
  float*    wp     = (float*)alloc((size_t)N * 4);
  int*      rowptr = (int*)alloc((size_t)(N + 1) * 4);
  int*      bcnt   = (int*)alloc(256 * 16 * 4);
  int*      bbase  = (int*)alloc(256 * 4);
  int*      gcur   = (int*)alloc(256 * 16 * 4);
  int*      rcnt   = (int*)alloc(256 * 16 * 4);
  int*      rbase  = (int*)alloc(256 * 4);
  int*      rcur   = (int*)alloc(256 * 16 * 4);
  float*    part   = (float*)alloc((size_t)NBU * CH * 4);
  ushort*   Wt1    = (ushort*)alloc(128 * 128 * 2);
  ushort*   Wt2    = (ushort*)alloc(128 * 128 * 2);
  float*    b1p    = (float*)alloc(CH * 4);
  float*    b2p    = (float*)alloc(CH * 4);
  int*      src    = (int*)alloc((size_t)E * 4);
  unsigned* cpk    = (unsigned*)alloc((size_t)E * 4);
  unsigned* rpk    = (unsigned*)alloc((size_t)E * 4);
  uint4*    hlo    = (uint4*)alloc((size_t)N * 64);  // fp8 plane ch 0..63
  uint4*    hhi    = (uint4*)alloc((size_t)N * 64);
  uint4*    xlo    = (uint4*)alloc((size_t)N * 64);
  uint4*    xhi    = (uint4*)alloc((size_t)N * 64);

  const int nCk = (E + CHUNK - 1) / CHUNK;

  // ---- preprocessing
  k_setup<<<1, 256, 0, stream>>>((const int*)ei, flag, bcnt, rcnt,
                                 W1, b1, W2, b2, Wt1, Wt2, b1p, b2p);
  kb_count<<<nCk, 256, 0, stream>>>(ei, flag, bcnt, rcnt, E, N);
  kb_scan<<<1, 256, 0, stream>>>(bcnt, bbase, gcur, rcnt, rbase, rcur, rowptr, NB, N);
  kb_scatter2<<<nCk, 256, 0, stream>>>(ei, flag, gcur, rcur, cpk, rpk, E, N);
  kb_csr<<<NB, 1024, 0, stream>>>(cpk, bcnt, bbase, rowptr, src, dinv, N);
  kb_wp<<<NB, 1024, 0, stream>>>(rpk, rcnt, rbase, dinv, wp, N);

  // ---- layers 1 & 2 (MFMA GEMMs + split-plane gather-aggregates)
  const int gblocks = (N + 63) / 64;
  dim3 pblk(4, 64);
  dim3 pgrid((N + 63) / 64);

  k_gemm_m<0><<<gblocks, 256, 0, stream>>>(x, nullptr, Wt1, dinv, (uint2*)hlo, (uint2*)hhi, N);
  k_aggp<<<pgrid, pblk, 0, stream>>>(hlo, dinv, rowptr, src, b1p,      xlo, N);
  k_aggp<<<pgrid, pblk, 0, stream>>>(hhi, dinv, rowptr, src, b1p + 64, xhi, N);
  k_gemm_m<1><<<gblocks, 256, 0, stream>>>(xlo, xhi, Wt2, dinv, (uint2*)hlo, (uint2*)hhi, N);
  k_aggp<<<pgrid, pblk, 0, stream>>>(hlo, dinv, rowptr, src, b2p,      xlo, N);
  k_aggp<<<pgrid, pblk, 0, stream>>>(hhi, dinv, rowptr, src, b2p + 64, xhi, N);

  // ---- layer 3 collapsed
  k_usumf<<<NBU, dim3(8, 32), 0, stream>>>(xlo, xhi, wp, dinv, part, N);
  k_final<<<1, 1024, 0, stream>>>(part, W3, b3, Wl, bl, out, 1.0f / (float)N);
}

// Round 13
// 310.801 us; speedup vs baseline: 1.6201x; 1.0236x over previous
//
#include <hip/hip_runtime.h>

#define CH 128
#define CHUNK 4096
#define NBU 256   // k_usumf grid

typedef float v2f __attribute__((ext_vector_type(2)));
typedef __attribute__((ext_vector_type(8))) short bf16x8;   // 8 bf16 (4 VGPRs)
typedef __attribute__((ext_vector_type(4))) float f32x4;    // MFMA acc

// ---------------------------------------------------------------- fp8 helpers (OCP e4m3)

__device__ __forceinline__ void fp8acc4(unsigned w, float* a) {
  v2f p0 = __builtin_amdgcn_cvt_pk_f32_fp8(w, false);
  v2f p1 = __builtin_amdgcn_cvt_pk_f32_fp8(w, true);
  a[0] += p0.x; a[1] += p0.y; a[2] += p1.x; a[3] += p1.y;
}
__device__ __forceinline__ void fp8acc16(uint4 v, float* a) {
  fp8acc4(v.x, a); fp8acc4(v.y, a + 4); fp8acc4(v.z, a + 8); fp8acc4(v.w, a + 12);
}
__device__ __forceinline__ void fp8wacc4(unsigned w, float wt, float* a) {
  v2f p0 = __builtin_amdgcn_cvt_pk_f32_fp8(w, false);
  v2f p1 = __builtin_amdgcn_cvt_pk_f32_fp8(w, true);
  a[0] += wt * p0.x; a[1] += wt * p0.y; a[2] += wt * p1.x; a[3] += wt * p1.y;
}
__device__ __forceinline__ unsigned fp8pk4(float a, float b, float c, float d) {
  int w = 0;
  w = __builtin_amdgcn_cvt_pk_fp8_f32(a, b, w, false);
  w = __builtin_amdgcn_cvt_pk_fp8_f32(c, d, w, true);
  return (unsigned)w;
}

// ---------------------------------------------------------------- bf16 helpers

__device__ __forceinline__ unsigned bfpack2(float a, float b) {
  unsigned ua = __float_as_uint(a); ua += 0x7FFF + ((ua >> 16) & 1);
  unsigned ub = __float_as_uint(b); ub += 0x7FFF + ((ub >> 16) & 1);
  return (ua >> 16) | (ub & 0xFFFF0000u);
}
__device__ __forceinline__ ushort bf16of(float a) {
  unsigned ua = __float_as_uint(a); ua += 0x7FFF + ((ua >> 16) & 1);
  return (ushort)(ua >> 16);
}
__device__ __forceinline__ uint2 fp8tobf4(unsigned w) {  // 4 fp8 -> 4 bf16
  v2f p0 = __builtin_amdgcn_cvt_pk_f32_fp8(w, false);
  v2f p1 = __builtin_amdgcn_cvt_pk_f32_fp8(w, true);
  return make_uint2(bfpack2(p0.x, p0.y), bfpack2(p1.x, p1.y));
}

// ---------------------------------------------------------------- utilities

__device__ __forceinline__ int edge_at(const void* ei, long long i, int is64) {
  if (is64) return (int)((const long long*)ei)[i];
  return ((const int*)ei)[i];
}

// merged setup: dtype detect + counter zero + bf16 weight prep (1 block)
__global__ void k_setup(const int* ei, int* flag, int* bcnt, int* rcnt,
                        const float* __restrict__ W1, const float* __restrict__ b1,
                        const float* __restrict__ W2, const float* __restrict__ b2,
                        ushort* __restrict__ Wt1, ushort* __restrict__ Wt2,
                        float* __restrict__ b1p, float* __restrict__ b2p) {
  int t = threadIdx.x;
  if (t == 0) {
    int is64 = 1;
    for (int k = 1; k < 128; k += 2)
      if (ei[k] != 0) { is64 = 0; break; }
    *flag = is64;
  }
  for (int i = t; i < 256 * 16; i += 256) { bcnt[i] = 0; rcnt[i] = 0; }
  for (int i = t; i < 128 * 128; i += 256) {
    int n = i >> 7, k = i & 127;
    Wt1[i] = bf16of(W1[(size_t)k * CH + n]);
    int ko = (k & 7) * 16 + (k >> 3);
    Wt2[i] = bf16of(W2[(size_t)ko * CH + n]);
  }
  if (t < CH) {
    int o = (t & 7) * 16 + (t >> 3);
    b1p[t] = b1[o];
    b2p[t] = b2[o];
  }
}

// P1: per-bucket edge counts for BOTH c-buckets and r-buckets
__global__ __launch_bounds__(256) void kb_count(const void* ei, const int* flag,
                                                int* bcnt, int* rcnt, int E, int N) {
  __shared__ int hist[256], rhist[256];
  int t = threadIdx.x;
  hist[t] = 0; rhist[t] = 0;
  __syncthreads();
  int f = *flag;
  for (int e = blockIdx.x * 256 + t; e < E; e += gridDim.x * 256) {
    int r = edge_at(ei, e, f);
    int c = edge_at(ei, (long long)E + e, f);
    if ((unsigned)r < (unsigned)N && (unsigned)c < (unsigned)N) {
      atomicAdd(&hist[c >> 8], 1);
      atomicAdd(&rhist[r >> 8], 1);
    }
  }
  __syncthreads();
  if (hist[t] > 0) atomicAdd(&bcnt[t * 16], hist[t]);
  if (rhist[t] > 0) atomicAdd(&rcnt[t * 16], rhist[t]);
}

// P2: scan both bucket-count arrays -> bases + cursors; rowptr[N]=total
__global__ void kb_scan(const int* bcnt, int* bbase, int* gcursor,
                        const int* rcnt, int* rbase, int* rcursor,
                        int* rowptr, int NB, int N) {
  __shared__ int tmp[256];
  int t = threadIdx.x;
  int v = (t < NB) ? bcnt[t * 16] : 0;
  tmp[t] = v;
  __syncthreads();
  for (int off = 1; off < 256; off <<= 1) {
    int u = (t >= off) ? tmp[t - off] : 0;
    __syncthreads();
    tmp[t] += u;
    __syncthreads();
  }
  bbase[t] = tmp[t] - v;
  gcursor[t * 16] = tmp[t] - v;
  if (t == 255) rowptr[N] = tmp[255];
  __syncthreads();
  int rv = (t < NB) ? rcnt[t * 16] : 0;
  tmp[t] = rv;
  __syncthreads();
  for (int off = 1; off < 256; off <<= 1) {
    int u = (t >= off) ? tmp[t - off] : 0;
    __syncthreads();
    tmp[t] += u;
    __syncthreads();
  }
  rbase[t] = tmp[t] - rv;
  rcursor[t * 16] = tmp[t] - rv;
}

// P3: merged dual bucket-sort, DIRECT global run writes (no LDS stage — R12's
// 920k LDS conflicts came from the 8B stage scatter). Per chunk: hist ->
// one global atomic per non-empty bucket -> per-edge LDS cursor + 4B store
// into the chunk's private run. Records: cpk = r|((c&255)<<24), rpk mirrored.
__global__ __launch_bounds__(256) void kb_scatter2(const void* ei, const int* flag,
                                                   int* gcur, int* rcur,
                                                   unsigned* __restrict__ cpk,
                                                   unsigned* __restrict__ rpk,
                                                   int E, int N) {
  __shared__ int hist[256], lcur[256], gbl[256];
  int t = threadIdx.x;
  int e0 = blockIdx.x * CHUNK;
  int f = *flag;
  int rr[16], cc[16];
#pragma unroll
  for (int k = 0; k < 16; ++k) {
    int e = e0 + k * 256 + t;
    rr[k] = 0; cc[k] = -1;
    if (e < E) {
      int r = edge_at(ei, e, f);
      int c = edge_at(ei, (long long)E + e, f);
      if ((unsigned)r < (unsigned)N && (unsigned)c < (unsigned)N) { rr[k] = r; cc[k] = c; }
    }
  }
  // ---- pass 1: key = c
  hist[t] = 0;
  __syncthreads();
#pragma unroll
  for (int k = 0; k < 16; ++k)
    if (cc[k] >= 0) atomicAdd(&hist[cc[k] >> 8], 1);
  __syncthreads();
  if (hist[t] > 0) gbl[t] = atomicAdd(&gcur[t * 16], hist[t]);
  lcur[t] = 0;
  __syncthreads();
#pragma unroll
  for (int k = 0; k < 16; ++k) {
    if (cc[k] >= 0) {
      int b = cc[k] >> 8;
      int pos = atomicAdd(&lcur[b], 1);
      cpk[gbl[b] + pos] = (unsigned)rr[k] | ((unsigned)(cc[k] & 255) << 24);
    }
  }
  __syncthreads();
  // ---- pass 2: key = r
  hist[t] = 0;
  __syncthreads();
#pragma unroll
  for (int k = 0; k < 16; ++k)
    if (cc[k] >= 0) atomicAdd(&hist[rr[k] >> 8], 1);
  __syncthreads();
  if (hist[t] > 0) gbl[t] = atomicAdd(&rcur[t * 16], hist[t]);
  lcur[t] = 0;
  __syncthreads();
#pragma unroll
  for (int k = 0; k < 16; ++k) {
    if (cc[k] >= 0) {
      int b = rr[k] >> 8;
      int pos = atomicAdd(&lcur[b], 1);
      rpk[gbl[b] + pos] = (unsigned)cc[k] | ((unsigned)(rr[k] & 255) << 24);
    }
  }
}

// P4: per-bucket CSR build + dinv from packed c-sorted records.
__global__ __launch_bounds__(1024) void kb_csr(const unsigned* __restrict__ cpk,
                                               const int* __restrict__ bcnt,
                                               const int* __restrict__ bbase,
                                               int* rowptr, int* src,
                                               float* dinv, int N) {
  __shared__ int hist[256], lcur[256], tmp[256];
  int t = threadIdx.x;
  int b = blockIdx.x;
  int node0 = b << 8;
  int nn = min(256, N - node0);
  int base = bbase[b];
  int cnt = bcnt[b * 16];
  if (t < 256) hist[t] = 0;
  __syncthreads();
  for (int j = t; j < cnt; j += 1024)
    atomicAdd(&hist[cpk[base + j] >> 24], 1);
  __syncthreads();
  if (t < 256) tmp[t] = hist[t];
  __syncthreads();
  for (int off = 1; off < 256; off <<= 1) {
    int u = (t < 256 && t >= off) ? tmp[t - off] : 0;
    __syncthreads();
    if (t < 256) tmp[t] += u;
    __syncthreads();
  }
  if (t < 256) {
    int v = hist[t];
    lcur[t] = tmp[t] - v;
    if (t < nn) {
      rowptr[node0 + t] = base + tmp[t] - v;
      dinv[node0 + t] = rsqrtf((float)(v + 1));  // +1 self-loop
    }
  }
  __syncthreads();
  for (int j = t; j < cnt; j += 1024) {
    unsigned w = cpk[base + j];
    int pos = atomicAdd(&lcur[w >> 24], 1);
    src[base + pos] = (int)(w & 0xFFFFFF);
  }
}

// P5: wp from packed r-sorted records — LDS atomics only
__global__ __launch_bounds__(1024) void kb_wp(const unsigned* __restrict__ rpk,
                                              const int* __restrict__ rcnt,
                                              const int* __restrict__ rbase,
                                              const float* __restrict__ dinv,
                                              float* __restrict__ wp, int N) {
  __shared__ float wpl[256];
  int t = threadIdx.x;
  int b = blockIdx.x;
  int node0 = b << 8;
  int nn = min(256, N - node0);
  int base = rbase[b];
  int cnt = rcnt[b * 16];
  if (t < 256) wpl[t] = 0.f;
  __syncthreads();
  for (int j = t; j < cnt; j += 1024) {
    unsigned w = rpk[base + j];
    atomicAdd(&wpl[w >> 24], dinv[w & 0xFFFFFF]);
  }
  __syncthreads();
  if (t < nn) wp[node0 + t] = wpl[t];
}

// ---------------------------------------------------------------- MFMA GEMM
// Output split into two 64B fp8 planes (ch_new 0..63 / 64..127) for L2-resident aggs.
template <int FP8A>
__global__ __launch_bounds__(256) void k_gemm_m(const void* __restrict__ Alo,
                                                const void* __restrict__ Ahi,
                                                const ushort* __restrict__ Wt,
                                                const float* __restrict__ dinv,
                                                uint2* __restrict__ Clo,
                                                uint2* __restrict__ Chi, int N) {
  __shared__ __align__(16) ushort As[64 * 136];
  __shared__ __align__(16) ushort Bs[128 * 136];
  int t = threadIdx.x;
  int row0 = blockIdx.x * 64;

  if (FP8A == 0) {
    const float4* A = (const float4*)Alo;  // [N][32]
    int k4 = t & 31, m0 = t >> 5;
    for (int mm = m0; mm < 64; mm += 8) {
      int gr = row0 + mm;
      float4 v = make_float4(0.f, 0.f, 0.f, 0.f);
      if (gr < N) v = A[(size_t)gr * 32 + k4];
      *(uint2*)&As[mm * 136 + k4 * 4] = make_uint2(bfpack2(v.x, v.y), bfpack2(v.z, v.w));
    }
  } else {
    const uint4* A0 = (const uint4*)Alo;  // [N][4] lo plane
    const uint4* A1 = (const uint4*)Ahi;  // [N][4] hi plane
    int k8 = t & 7, m0 = t >> 3;
    for (int mm = m0; mm < 64; mm += 32) {
      int gr = row0 + mm;
      uint4 v = make_uint4(0, 0, 0, 0);
      if (gr < N) v = (k8 < 4) ? A0[(size_t)gr * 4 + k8] : A1[(size_t)gr * 4 + k8 - 4];
      ushort* d = &As[mm * 136 + k8 * 16];
      *(uint2*)&d[0]  = fp8tobf4(v.x);
      *(uint2*)&d[4]  = fp8tobf4(v.y);
      *(uint2*)&d[8]  = fp8tobf4(v.z);
      *(uint2*)&d[12] = fp8tobf4(v.w);
    }
  }
  {
    const uint4* W4 = (const uint4*)Wt;
    int rw = t >> 1, half = t & 1;
#pragma unroll
    for (int i = 0; i < 8; ++i) {
      uint4 v = W4[rw * 16 + half * 8 + i];
      *(uint4*)&Bs[rw * 136 + half * 64 + i * 8] = v;
    }
  }
  __syncthreads();

  int lane = t & 63, w = t >> 6;
  int m = lane & 15, quad = lane >> 4;
  f32x4 acc[8] = {};
#pragma unroll
  for (int kb = 0; kb < 128; kb += 32) {
    bf16x8 af = *(const bf16x8*)&As[(w * 16 + m) * 136 + kb + quad * 8];
#pragma unroll
    for (int nt = 0; nt < 8; ++nt) {
      bf16x8 bfv = *(const bf16x8*)&Bs[(nt * 16 + m) * 136 + kb + quad * 8];
      acc[nt] = __builtin_amdgcn_mfma_f32_16x16x32_bf16(af, bfv, acc[nt], 0, 0, 0);
    }
  }
  uint2* pl = (m < 8) ? Clo : Chi;
#pragma unroll
  for (int reg = 0; reg < 4; ++reg) {
    int gr = row0 + w * 16 + quad * 4 + reg;
    if (gr < N) {
      float s = dinv[gr];
      unsigned w0 = fp8pk4(acc[0][reg] * s, acc[1][reg] * s, acc[2][reg] * s, acc[3][reg] * s);
      unsigned w1 = fp8pk4(acc[4][reg] * s, acc[5][reg] * s, acc[6][reg] * s, acc[7][reg] * s);
      pl[(size_t)gr * 8 + (m & 7)] = make_uint2(w0, w1);
    }
  }
}

// ---------------------------------------------------------------- aggregate (fp8, one 64B plane)
// Working set per pass = N*64B = 3.2MB -> L2-resident per XCD.
__global__ __launch_bounds__(256) void k_aggp(const uint4* __restrict__ hh,  // [N][4]
                                              const float* __restrict__ dinv,
                                              const int* __restrict__ rowptr,
                                              const int* __restrict__ src,
                                              const float* __restrict__ biasH,
                                              uint4* __restrict__ outp, int N) {
  int tx = threadIdx.x;  // 0..3 : 16-channel chunk
  int ty = threadIdx.y;  // 0..63: node slot
  float bv[16];
#pragma unroll
  for (int i = 0; i < 16; ++i) bv[i] = biasH[tx * 16 + i];

  for (int c = blockIdx.x * 64 + ty; c < N; c += gridDim.x * 64) {
    float acc[16] = {};
    fp8acc16(hh[(size_t)c * 4 + tx], acc);  // self-loop
    int j = rowptr[c], je = rowptr[c + 1];
    for (; j + 8 <= je; j += 8) {
      int r0 = src[j + 0], r1 = src[j + 1], r2 = src[j + 2], r3 = src[j + 3];
      int r4 = src[j + 4], r5 = src[j + 5], r6 = src[j + 6], r7 = src[j + 7];
      uint4 v0 = hh[(size_t)r0 * 4 + tx];
      uint4 v1 = hh[(size_t)r1 * 4 + tx];
      uint4 v2 = hh[(size_t)r2 * 4 + tx];
      uint4 v3 = hh[(size_t)r3 * 4 + tx];
      uint4 v4 = hh[(size_t)r4 * 4 + tx];
      uint4 v5 = hh[(size_t)r5 * 4 + tx];
      uint4 v6 = hh[(size_t)r6 * 4 + tx];
      uint4 v7 = hh[(size_t)r7 * 4 + tx];
      fp8acc16(v0, acc); fp8acc16(v1, acc); fp8acc16(v2, acc); fp8acc16(v3, acc);
      fp8acc16(v4, acc); fp8acc16(v5, acc); fp8acc16(v6, acc); fp8acc16(v7, acc);
    }
    for (; j < je; ++j) fp8acc16(hh[(size_t)src[j] * 4 + tx], acc);
    float s = dinv[c];
    float o[16];
#pragma unroll
    for (int i = 0; i < 16; ++i) o[i] = fmaxf(acc[i] * s + bv[i], 0.f);
    uint4 ov;
    ov.x = fp8pk4(o[0], o[1], o[2], o[3]);
    ov.y = fp8pk4(o[4], o[5], o[6], o[7]);
    ov.z = fp8pk4(o[8], o[9], o[10], o[11]);
    ov.w = fp8pk4(o[12], o[13], o[14], o[15]);
    outp[(size_t)c * 4 + tx] = ov;
  }
}

// ---------------------------------------------------------------- layer-3 collapse
__global__ __launch_bounds__(256) void k_usumf(const uint4* __restrict__ xlo,
                                               const uint4* __restrict__ xhi,
                                               const float* __restrict__ wp,
                                               const float* __restrict__ dinv,
                                               float* __restrict__ partial, int N) {
  __shared__ float red[32][129];
  int tx = threadIdx.x;  // 0..7
  int ty = threadIdx.y;  // 0..31
  float acc[16] = {};
  for (int c = blockIdx.x * 32 + ty; c < N; c += gridDim.x * 32) {
    float d = dinv[c];
    float wt = (d + wp[c]) * d;
    uint4 v = (tx < 4) ? xlo[(size_t)c * 4 + tx] : xhi[(size_t)c * 4 + tx - 4];
    fp8wacc4(v.x, wt, acc); fp8wacc4(v.y, wt, acc + 4);
    fp8wacc4(v.z, wt, acc + 8); fp8wacc4(v.w, wt, acc + 12);
  }
#pragma unroll
  for (int i = 0; i < 16; ++i) red[ty][tx * 16 + i] = acc[i];
  __syncthreads();
  for (int s = 16; s > 0; s >>= 1) {
    if (ty < s) {
#pragma unroll
      for (int i = 0; i < 16; ++i) red[ty][tx * 16 + i] += red[ty + s][tx * 16 + i];
    }
    __syncthreads();
  }
  if (ty == 0) {
#pragma unroll
    for (int i = 0; i < 16; ++i)
      partial[(size_t)blockIdx.x * CH + tx * 16 + i] = red[0][tx * 16 + i];
  }
}

// ---------------------------------------------------------------- epilogue (1024 thr)
__global__ __launch_bounds__(1024) void k_final(const float* __restrict__ partial,
                                                const float* __restrict__ W3,
                                                const float* __restrict__ b3,
                                                const float* __restrict__ Wl,
                                                const float* __restrict__ bl,
                                                float* __restrict__ out, float invN) {
  __shared__ float us[CH];
  __shared__ float red[8][CH];
  int t = threadIdx.x;
  int ch = t & 127, g = t >> 7;
  float s = 0.f;
#pragma unroll
  for (int b = 0; b < 32; ++b)
    s += partial[(size_t)(g * 32 + b) * CH + ch];
  red[g][ch] = s;
  __syncthreads();
  if (g == 0) {
    float u = 0.f;
#pragma unroll
    for (int k = 1; k < 8; ++k) u += red[k][ch];
    us[ch] = (s + u) * invN;
  }
  __syncthreads();
  float p = 0.f;
#pragma unroll
  for (int k = 0; k < 16; ++k) {
    int kk = g * 16 + k;
    int ko = (kk & 7) * 16 + (kk >> 3);  // un-permute channel
    p += us[kk] * W3[(size_t)ko * CH + ch];
  }
  red[g][ch] = p;
  __syncthreads();
  if (g == 0) {
    float S = red[0][ch];
#pragma unroll
    for (int k = 1; k < 8; ++k) S += red[k][ch];
    us[ch] = (S + b3[ch]) * Wl[ch];
  }
  __syncthreads();
  for (int off = 64; off > 0; off >>= 1) {
    if (t < off) us[t] += us[t + off];
    __syncthreads();
  }
  if (t == 0) out[0] = 1.f / (1.f + expf(-(us[0] + bl[0])));
}

// ---------------------------------------------------------------- launch

extern "C" void kernel_launch(void* const* d_in, const int* in_sizes, int n_in,
                              void* d_out, int out_size, void* d_ws, size_t ws_size,
                              hipStream_t stream) {
  const float* x  = (const float*)d_in[0];
  const void*  ei = d_in[1];
  const float* W1 = (const float*)d_in[3];
  const float* b1 = (const float*)d_in[4];
  const float* W2 = (const float*)d_in[5];
  const float* b2 = (const float*)d_in[6];
  const float* W3 = (const float*)d_in[7];
  const float* b3 = (const float*)d_in[8];
  const float* Wl = (const float*)d_in[9];
  const float* bl = (const float*)d_in[10];
  float* out = (float*)d_out;

  const int N = in_sizes[0] / CH;
  const int E = in_sizes[1] / 2;
  const int NB = (N + 255) >> 8;

  char* ws = (char*)d_ws;
  size_t off = 0;
  auto alloc = [&](size_t bytes) -> void* {
    void* p = ws + off;
    off += (bytes + 511) & ~(size_t)511;
    return p;
  };
  int*      flag   = (int*)alloc(4);
  float*    dinv   = (float*)alloc((size_t)N * 4);
  float*    wp     = (float*)alloc((size_t)N * 4);
  int*      rowptr = (int*)alloc((size_t)(N + 1) * 4);
  int*      bcnt   = (int*)alloc(256 * 16 * 4);
  int*      bbase  = (int*)alloc(256 * 4);
  int*      gcur   = (int*)alloc(256 * 16 * 4);
  int*      rcnt   = (int*)alloc(256 * 16 * 4);
  int*      rbase  = (int*)alloc(256 * 4);
  int*      rcur   = (int*)alloc(256 * 16 * 4);
  float*    part   = (float*)alloc((size_t)NBU * CH * 4);
  ushort*   Wt1    = (ushort*)alloc(128 * 128 * 2);
  ushort*   Wt2    = (ushort*)alloc(128 * 128 * 2);
  float*    b1p    = (float*)alloc(CH * 4);
  float*    b2p    = (float*)alloc(CH * 4);
  int*      src    = (int*)alloc((size_t)E * 4);
  unsigned* cpk    = (unsigned*)alloc((size_t)E * 4);
  unsigned* rpk    = (unsigned*)alloc((size_t)E * 4);
  uint4*    hlo    = (uint4*)alloc((size_t)N * 64);  // fp8 plane ch 0..63
  uint4*    hhi    = (uint4*)alloc((size_t)N * 64);
  uint4*    xlo    = (uint4*)alloc((size_t)N * 64);
  uint4*    xhi    = (uint4*)alloc((size_t)N * 64);

  const int nCk = (E + CHUNK - 1) / CHUNK;

  // ---- preprocessing
  k_setup<<<1, 256, 0, stream>>>((const int*)ei, flag, bcnt, rcnt,
                                 W1, b1, W2, b2, Wt1, Wt2, b1p, b2p);
  kb_count<<<nCk, 256, 0, stream>>>(ei, flag, bcnt, rcnt, E, N);
  kb_scan<<<1, 256, 0, stream>>>(bcnt, bbase, gcur, rcnt, rbase, rcur, rowptr, NB, N);
  kb_scatter2<<<nCk, 256, 0, stream>>>(ei, flag, gcur, rcur, cpk, rpk, E, N);
  kb_csr<<<NB, 1024, 0, stream>>>(cpk, bcnt, bbase, rowptr, src, dinv, N);
  kb_wp<<<NB, 1024, 0, stream>>>(rpk, rcnt, rbase, dinv, wp, N);

  // ---- layers 1 & 2 (MFMA GEMMs + split-plane gather-aggregates)
  const int gblocks = (N + 63) / 64;
  dim3 pblk(4, 64);
  dim3 pgrid((N + 63) / 64);

  k_gemm_m<0><<<gblocks, 256, 0, stream>>>(x, nullptr, Wt1, dinv, (uint2*)hlo, (uint2*)hhi, N);
  k_aggp<<<pgrid, pblk, 0, stream>>>(hlo, dinv, rowptr, src, b1p,      xlo, N);
  k_aggp<<<pgrid, pblk, 0, stream>>>(hhi, dinv, rowptr, src, b1p + 64, xhi, N);
  k_gemm_m<1><<<gblocks, 256, 0, stream>>>(xlo, xhi, Wt2, dinv, (uint2*)hlo, (uint2*)hhi, N);
  k_aggp<<<pgrid, pblk, 0, stream>>>(hlo, dinv, rowptr, src, b2p,      xlo, N);
  k_aggp<<<pgrid, pblk, 0, stream>>>(hhi, dinv, rowptr, src, b2p + 64, xhi, N);

  // ---- layer 3 collapsed
  k_usumf<<<NBU, dim3(8, 32), 0, stream>>>(xlo, xhi, wp, dinv, part, N);
  k_final<<<1, 1024, 0, stream>>>(part, W3, b3, Wl, bl, out, 1.0f / (float)N);
}